// Round 1
// baseline (367.832 us; speedup 1.0000x reference)
//
#include <hip/hip_runtime.h>
#include <math.h>

typedef unsigned short u16;
typedef unsigned int u32;
typedef __attribute__((ext_vector_type(8))) short short8;   // 8 bf16 in 4 VGPRs (MFMA A/B frag)
typedef __attribute__((ext_vector_type(4))) float f32x4;    // MFMA C/D frag

#define EPS 1e-8f

// ---------- helpers ----------
__device__ inline float bf2f(u16 u) {
    union { u32 i; float f; } v; v.i = ((u32)u) << 16; return v.f;
}
__device__ inline u16 f2bf(float f) {  // RNE
    union { float f; u32 u; } v; v.f = f;
    u32 r = v.u + 0x7fffu + ((v.u >> 16) & 1u);
    return (u16)(r >> 16);
}
__device__ inline u32 pack2(float a, float b) {
    return (u32)f2bf(a) | ((u32)f2bf(b) << 16);
}
__device__ inline float wave_sum(float v) {
    for (int off = 32; off; off >>= 1) v += __shfl_xor(v, off, 64);
    return v;
}
__device__ inline float wave_max(float v) {
    for (int off = 32; off; off >>= 1) v = fmaxf(v, __shfl_xor(v, off, 64));
    return v;
}

// ---------- K1: normalize vis_global (fp32 + bf16), zero loss ----------
__global__ __launch_bounds__(256) void prep_vis(const float* __restrict__ vis,
                                                float* __restrict__ vis_n,
                                                u16* __restrict__ vis_nb,
                                                float* __restrict__ loss0)
{
    if (blockIdx.x == 0 && threadIdx.x == 0) loss0[0] = 0.0f;
    int wave = threadIdx.x >> 6, lane = threadIdx.x & 63;
    int b = blockIdx.x * 4 + wave;               // B = 512, grid 128
    const float* row = vis + b * 512 + lane * 8;
    float4 x0 = *(const float4*)row;
    float4 x1 = *(const float4*)(row + 4);
    float ss = x0.x*x0.x + x0.y*x0.y + x0.z*x0.z + x0.w*x0.w
             + x1.x*x1.x + x1.y*x1.y + x1.z*x1.z + x1.w*x1.w;
    ss = wave_sum(ss);
    float inv = 1.0f / fmaxf(sqrtf(ss), EPS);
    float4 y0, y1;
    y0.x = x0.x*inv; y0.y = x0.y*inv; y0.z = x0.z*inv; y0.w = x0.w*inv;
    y1.x = x1.x*inv; y1.y = x1.y*inv; y1.z = x1.z*inv; y1.w = x1.w*inv;
    *(float4*)(vis_n + b*512 + lane*8)     = y0;
    *(float4*)(vis_n + b*512 + lane*8 + 4) = y1;
    uint4 pk;
    pk.x = pack2(y0.x, y0.y); pk.y = pack2(y0.z, y0.w);
    pk.z = pack2(y1.x, y1.y); pk.w = pack2(y1.z, y1.w);
    *(uint4*)(vis_nb + b*512 + lane*8) = pk;
}

// ---------- K2: convert wk|wv (rows 512..1535 of in_proj_w) to bf16 ----------
__global__ __launch_bounds__(256) void cvt_wkv(const float* __restrict__ w, u16* __restrict__ wb)
{
    int i = (blockIdx.x * 256 + threadIdx.x) * 4;   // 1024*512 elems, grid 512
    float4 v = *(const float4*)(w + i);
    uint2 pk; pk.x = pack2(v.x, v.y); pk.y = pack2(v.z, v.w);
    *(uint2*)(wb + i) = pk;
}

// ---------- K3/K8: OUT[b0+r][j] = IN[b0+r]·W[j] + bias[j], 8 rows/block ----------
__global__ __launch_bounds__(256) void rowproj8(const float* __restrict__ IN,
                                                const float* __restrict__ W,
                                                const float* __restrict__ bias,
                                                float* __restrict__ OUT)
{
    __shared__ float sv[8 * 512];
    int t = threadIdx.x;
    int b0 = blockIdx.x * 8;
    const float4* src = (const float4*)(IN + b0 * 512);
    float4* dst4 = (float4*)sv;
    for (int i = t; i < 1024; i += 256) dst4[i] = src[i];
    __syncthreads();
    int j = blockIdx.y * 256 + t;                 // 512 outputs
    float acc[8];
    float bj = bias[j];
    for (int r = 0; r < 8; r++) acc[r] = bj;
    const float4* wr = (const float4*)(W + j * 512);
    for (int kk = 0; kk < 128; kk++) {
        float4 w = wr[kk];
        #pragma unroll
        for (int r = 0; r < 8; r++) {
            const float* vv = &sv[r * 512 + kk * 4];
            acc[r] += w.x*vv[0] + w.y*vv[1] + w.z*vv[2] + w.w*vv[3];
        }
    }
    for (int r = 0; r < 8; r++) OUT[(b0 + r) * 512 + j] = acc[r];
}

// ---------- K4: sims + bf16 conversion of text_features ----------
__global__ __launch_bounds__(256) void sims_convert(const float* __restrict__ tf,
                                                    const float* __restrict__ vis_n,
                                                    float* __restrict__ sims,
                                                    u16* __restrict__ Xb)
{
    int wave = threadIdx.x >> 6, lane = threadIdx.x & 63;
    int n = blockIdx.x * 4 + wave;                // 49152 rows, grid 12288
    int b = n / 96;
    const float* row = tf + (size_t)n * 512 + lane * 8;
    float4 x0 = *(const float4*)row;
    float4 x1 = *(const float4*)(row + 4);
    const float* vn = vis_n + b * 512 + lane * 8;
    float4 v0 = *(const float4*)vn;
    float4 v1 = *(const float4*)(vn + 4);
    float ss = x0.x*x0.x + x0.y*x0.y + x0.z*x0.z + x0.w*x0.w
             + x1.x*x1.x + x1.y*x1.y + x1.z*x1.z + x1.w*x1.w;
    float dt = x0.x*v0.x + x0.y*v0.y + x0.z*v0.z + x0.w*v0.w
             + x1.x*v1.x + x1.y*v1.y + x1.z*v1.z + x1.w*v1.w;
    ss = wave_sum(ss);
    dt = wave_sum(dt);
    float inv = 1.0f / fmaxf(sqrtf(ss), EPS);
    if (lane == 0) sims[n] = dt * inv;
    uint4 pk;
    pk.x = pack2(x0.x, x0.y); pk.y = pack2(x0.z, x0.w);
    pk.z = pack2(x1.x, x1.y); pk.w = pack2(x1.z, x1.w);
    *(uint4*)(Xb + (size_t)n * 512 + lane * 8) = pk;
}

// ---------- K5: cluster scores ----------
__global__ __launch_bounds__(128) void cluster_kernel(const float* __restrict__ sims,
                                                      float* __restrict__ out_cs)
{
    int b = blockIdx.x, t = threadIdx.x;
    __shared__ float s[96], srt[96];
    if (t < 96) s[t] = sims[b * 96 + t];
    __syncthreads();
    if (t < 96) {
        float v = s[t]; int r = 0;
        for (int j = 0; j < 96; j++) {
            float u = s[j];
            r += (u > v) || (u == v && j < t);   // descending rank, unique
        }
        srt[r] = v;
    }
    __syncthreads();
    if (t < 3) {
        float mean = 0.f;
        for (int i = 0; i < 32; i++) mean += srt[t * 32 + i];
        mean *= (1.0f / 32.0f);
        float var = 0.f;
        for (int i = 0; i < 32; i++) { float d = srt[t * 32 + i] - mean; var += d * d; }
        var *= (1.0f / 31.0f);                   // ddof=1
        out_cs[b * 3 + t] = mean / (sqrtf(var) + 1e-6f);
    }
}

// ---------- K6/K10: C = A(Mx512) @ Bm(Nx512)^T  (bf16 MFMA 16x16x32) ----------
template<bool OUTBF>
__global__ __launch_bounds__(256) void gemm_bt(const u16* __restrict__ A,
                                               const u16* __restrict__ Bm,
                                               const float* __restrict__ bias,
                                               u16* __restrict__ Cb,
                                               float* __restrict__ Cf)
{
    __shared__ __align__(16) u16 As[128 * 64];
    __shared__ __align__(16) u16 Bs[128 * 64];
    const int t = threadIdx.x;
    const int lane = t & 63;
    const int wave = t >> 6;
    const int m0 = blockIdx.x * 128;
    const int n0 = blockIdx.y * 128;
    const int wm = (wave >> 1) * 64;
    const int wn = (wave & 1) * 64;
    const int l16 = lane & 15, quad = lane >> 4;
    const int srow = t >> 3;            // 0..31
    const int scol = (t & 7) * 8;       // 0..56 elements

    f32x4 acc[4][4];
    for (int i = 0; i < 4; i++)
        for (int j = 0; j < 4; j++)
            for (int e = 0; e < 4; e++) acc[i][j][e] = 0.f;

    for (int ko = 0; ko < 512; ko += 64) {
        __syncthreads();
        #pragma unroll
        for (int i = 0; i < 4; i++) {
            int row = i * 32 + srow;
            *(uint4*)&As[row * 64 + scol] = *(const uint4*)&A[(m0 + row) * 512 + ko + scol];
            *(uint4*)&Bs[row * 64 + scol] = *(const uint4*)&Bm[(n0 + row) * 512 + ko + scol];
        }
        __syncthreads();
        #pragma unroll
        for (int ks = 0; ks < 2; ks++) {
            short8 af[4], bfr[4];
            #pragma unroll
            for (int i = 0; i < 4; i++)
                af[i] = *(const short8*)&As[(wm + i * 16 + l16) * 64 + ks * 32 + quad * 8];
            #pragma unroll
            for (int j = 0; j < 4; j++)
                bfr[j] = *(const short8*)&Bs[(wn + j * 16 + l16) * 64 + ks * 32 + quad * 8];
            #pragma unroll
            for (int i = 0; i < 4; i++)
                #pragma unroll
                for (int j = 0; j < 4; j++)
                    acc[i][j] = __builtin_amdgcn_mfma_f32_16x16x32_bf16(af[i], bfr[j], acc[i][j], 0, 0, 0);
        }
    }
    // epilogue: D row = quad*4+r, col = l16 (verified m89/m91 layout)
    for (int i = 0; i < 4; i++) {
        int row = m0 + wm + i * 16 + quad * 4;
        for (int j = 0; j < 4; j++) {
            int col = n0 + wn + j * 16 + l16;
            float bv = bias ? bias[col] : 0.f;
            for (int r = 0; r < 4; r++) {
                float vv = acc[i][j][r] + bv;
                if (OUTBF) Cb[(size_t)(row + r) * 1024 + col] = f2bf(vv);
                else       Cf[(size_t)(row + r) * 1024 + col] = vv;
            }
        }
    }
}

// ---------- K7: attention, one wave per (b,h) ----------
__global__ __launch_bounds__(64) void attn_kernel(const float* __restrict__ q,
                                                  const u16* __restrict__ kv,
                                                  float* __restrict__ ctx)
{
    int b = blockIdx.x, h = blockIdx.y;
    int lane = threadIdx.x;
    __shared__ float sq[64];
    __shared__ float sp[96];
    sq[lane] = q[b * 512 + h * 64 + lane];
    __syncthreads();

    float s0, s1 = -1e30f;
    {
        int m = lane;
        const u16* kr = kv + (size_t)(b * 96 + m) * 1024 + h * 64;
        float dot = 0.f;
        #pragma unroll
        for (int c = 0; c < 2; c++) {
            uint4 raw = *(const uint4*)(kr + c * 32);      // wait: 16B = 8 elems
            // (unused; replaced below)
        }
        dot = 0.f;
        #pragma unroll
        for (int c = 0; c < 8; c++) {
            uint2 raw = *(const uint2*)(kr + c * 8);       // 8B = 4 bf16
            uint2 raw2 = *(const uint2*)(kr + c * 8 + 4);
            dot += bf2f((u16)(raw.x & 0xffff))  * sq[c*8+0];
            dot += bf2f((u16)(raw.x >> 16))     * sq[c*8+1];
            dot += bf2f((u16)(raw.y & 0xffff))  * sq[c*8+2];
            dot += bf2f((u16)(raw.y >> 16))     * sq[c*8+3];
            dot += bf2f((u16)(raw2.x & 0xffff)) * sq[c*8+4];
            dot += bf2f((u16)(raw2.x >> 16))    * sq[c*8+5];
            dot += bf2f((u16)(raw2.y & 0xffff)) * sq[c*8+6];
            dot += bf2f((u16)(raw2.y >> 16))    * sq[c*8+7];
        }
        s0 = dot * 0.125f;
    }
    if (lane < 32) {
        int m = 64 + lane;
        const u16* kr = kv + (size_t)(b * 96 + m) * 1024 + h * 64;
        float dot = 0.f;
        #pragma unroll
        for (int c = 0; c < 8; c++) {
            uint2 raw = *(const uint2*)(kr + c * 8);
            uint2 raw2 = *(const uint2*)(kr + c * 8 + 4);
            dot += bf2f((u16)(raw.x & 0xffff))  * sq[c*8+0];
            dot += bf2f((u16)(raw.x >> 16))     * sq[c*8+1];
            dot += bf2f((u16)(raw.y & 0xffff))  * sq[c*8+2];
            dot += bf2f((u16)(raw.y >> 16))     * sq[c*8+3];
            dot += bf2f((u16)(raw2.x & 0xffff)) * sq[c*8+4];
            dot += bf2f((u16)(raw2.x >> 16))    * sq[c*8+5];
            dot += bf2f((u16)(raw2.y & 0xffff)) * sq[c*8+6];
            dot += bf2f((u16)(raw2.y >> 16))    * sq[c*8+7];
        }
        s1 = dot * 0.125f;
    }
    float mx = fmaxf(s0, s1);
    mx = wave_max(mx);
    float e0 = expf(s0 - mx);
    float e1 = (lane < 32) ? expf(s1 - mx) : 0.f;
    float tot = wave_sum(e0 + e1);
    float invt = 1.0f / tot;
    sp[lane] = e0 * invt;
    if (lane < 32) sp[64 + lane] = e1 * invt;
    __syncthreads();

    float a = 0.f;
    const u16* vbase = kv + 512 + h * 64 + lane;
    for (int m = 0; m < 96; m++)
        a += sp[m] * bf2f(vbase[(size_t)(b * 96 + m) * 1024]);
    ctx[b * 512 + h * 64 + lane] = a;
}

// ---------- K9: build normalized negatives (bf16) + pos_sim ----------
__global__ __launch_bounds__(256) void negs_build(const float* __restrict__ corrected,
                                                  const float* __restrict__ tm,
                                                  const float* __restrict__ vis_n,
                                                  u16* __restrict__ negs_nb,
                                                  float* __restrict__ pos)
{
    int wave = threadIdx.x >> 6, lane = threadIdx.x & 63;
    int j = blockIdx.x * 4 + wave;               // 0..1023, grid 256
    const float* src = (j < 512) ? (corrected + j * 512) : (tm + j * 512);
    const float* row = src + lane * 8;
    float4 x0 = *(const float4*)row;
    float4 x1 = *(const float4*)(row + 4);
    float ss = x0.x*x0.x + x0.y*x0.y + x0.z*x0.z + x0.w*x0.w
             + x1.x*x1.x + x1.y*x1.y + x1.z*x1.z + x1.w*x1.w;
    float dt = 0.f;
    if (j < 512) {
        const float* vn = vis_n + j * 512 + lane * 8;
        float4 v0 = *(const float4*)vn;
        float4 v1 = *(const float4*)(vn + 4);
        dt = x0.x*v0.x + x0.y*v0.y + x0.z*v0.z + x0.w*v0.w
           + x1.x*v1.x + x1.y*v1.y + x1.z*v1.z + x1.w*v1.w;
    }
    ss = wave_sum(ss);
    dt = wave_sum(dt);
    float inv = 1.0f / fmaxf(sqrtf(ss), EPS);
    float4 y0, y1;
    y0.x = x0.x*inv; y0.y = x0.y*inv; y0.z = x0.z*inv; y0.w = x0.w*inv;
    y1.x = x1.x*inv; y1.y = x1.y*inv; y1.z = x1.z*inv; y1.w = x1.w*inv;
    uint4 pk;
    pk.x = pack2(y0.x, y0.y); pk.y = pack2(y0.z, y0.w);
    pk.z = pack2(y1.x, y1.y); pk.w = pack2(y1.z, y1.w);
    *(uint4*)(negs_nb + j * 512 + lane * 8) = pk;
    if (j < 512 && lane == 0) pos[j] = dt * inv;
}

// ---------- K11: top-5 over 1536-multiset + loss ----------
__global__ __launch_bounds__(256) void topk_loss(const float* __restrict__ ns,
                                                 const float* __restrict__ pos,
                                                 const float* __restrict__ tau_p_log,
                                                 const float* __restrict__ tau_n_log,
                                                 float* __restrict__ out_loss)
{
    int b = blockIdx.x, t = threadIdx.x;
    __shared__ float sv[1536];
    __shared__ float rv[256];
    __shared__ int   ri[256];
    __shared__ float stop5[5];
    const float* row = ns + b * 1024;
    for (int i = t; i < 1536; i += 256) {
        float v;
        if (i < 1024) v = row[i & 511];          // corr sims appear twice (roll + mem)
        else          v = row[512 + (i - 1024)]; // memory sims
        sv[i] = v;
    }
    __syncthreads();
    for (int r = 0; r < 5; r++) {
        float best = -1e30f; int bi = 0;
        for (int i = t; i < 1536; i += 256)
            if (sv[i] > best) { best = sv[i]; bi = i; }
        rv[t] = best; ri[t] = bi;
        __syncthreads();
        for (int s = 128; s > 0; s >>= 1) {
            if (t < s) {
                if (rv[t + s] > rv[t]) { rv[t] = rv[t + s]; ri[t] = ri[t + s]; }
            }
            __syncthreads();
        }
        if (t == 0) { stop5[r] = rv[0]; sv[ri[0]] = -1e30f; }
        __syncthreads();
    }
    if (t == 0) {
        float tp = expf(tau_p_log[0]), tn = expf(tau_n_log[0]);
        float p = expf(pos[b] / tp);
        float n = 0.f;
        for (int r = 0; r < 5; r++) n += expf(stop5[r] / tn);
        float term = logf(p / (p + n + 1e-8f));
        atomicAdd(out_loss, -term * (1.0f / 512.0f));
    }
}

// ---------- launch ----------
extern "C" void kernel_launch(void* const* d_in, const int* in_sizes, int n_in,
                              void* d_out, int out_size, void* d_ws, size_t ws_size,
                              hipStream_t stream) {
    const float* vis = (const float*)d_in[0];
    const float* tf  = (const float*)d_in[1];
    const float* ipw = (const float*)d_in[2];
    const float* ipb = (const float*)d_in[3];
    const float* opw = (const float*)d_in[4];
    const float* opb = (const float*)d_in[5];
    const float* tm  = (const float*)d_in[6];
    const float* tpl = (const float*)d_in[7];
    const float* tnl = (const float*)d_in[8];

    float* out       = (float*)d_out;
    float* out_loss  = out;
    float* out_corr  = out + 1;                  // (512,512)
    float* out_cs    = out + 1 + 512 * 512;      // (512,3)

    char* p = (char*)d_ws;
    auto alloc = [&](size_t bytes) { char* r = p; p += (bytes + 255) & ~(size_t)255; return r; };
    float* vis_n  = (float*)alloc(512 * 512 * 4);
    u16*   vis_nb = (u16*)  alloc(512 * 512 * 2);
    float* qws    = (float*)alloc(512 * 512 * 4);
    float* simsws = (float*)alloc(512 * 96 * 4);
    u16*   Xb     = (u16*)  alloc((size_t)49152 * 512 * 2);
    u16*   Wkvb   = (u16*)  alloc(1024 * 512 * 2);
    u16*   KV     = (u16*)  alloc((size_t)49152 * 1024 * 2);
    float* ctx    = (float*)alloc(512 * 512 * 4);
    u16*   negsb  = (u16*)  alloc(1024 * 512 * 2);
    float* ns     = (float*)alloc(512 * 1024 * 4);
    float* pos    = (float*)alloc(512 * 4);

    prep_vis<<<128, 256, 0, stream>>>(vis, vis_n, vis_nb, out_loss);
    cvt_wkv<<<512, 256, 0, stream>>>(ipw + 512 * 512, Wkvb);
    rowproj8<<<dim3(64, 2), 256, 0, stream>>>(vis, ipw, ipb, qws);
    sims_convert<<<12288, 256, 0, stream>>>(tf, vis_n, simsws, Xb);
    cluster_kernel<<<512, 128, 0, stream>>>(simsws, out_cs);
    gemm_bt<true><<<dim3(384, 8), 256, 0, stream>>>(Xb, Wkvb, ipb + 512, KV, nullptr);
    attn_kernel<<<dim3(512, 8), 64, 0, stream>>>(qws, KV, ctx);
    rowproj8<<<dim3(64, 2), 256, 0, stream>>>(ctx, opw, opb, out_corr);
    negs_build<<<256, 256, 0, stream>>>(out_corr, tm, vis_n, negsb, pos);
    gemm_bt<false><<<dim3(4, 8), 256, 0, stream>>>(vis_nb, negsb, nullptr, nullptr, ns);
    topk_loss<<<512, 256, 0, stream>>>(ns, pos, tpl, tnl, out_loss);
}

// Round 2
// 318.632 us; speedup vs baseline: 1.1544x; 1.1544x over previous
//
#include <hip/hip_runtime.h>
#include <math.h>

typedef unsigned short u16;
typedef unsigned int u32;
typedef __attribute__((ext_vector_type(8))) short short8;   // 8 bf16 in 4 VGPRs (MFMA A/B frag)
typedef __attribute__((ext_vector_type(4))) float f32x4;    // MFMA C/D frag

#define EPS 1e-8f

// ---------- helpers ----------
__device__ inline float bf2f(u16 u) {
    union { u32 i; float f; } v; v.i = ((u32)u) << 16; return v.f;
}
__device__ inline u16 f2bf(float f) {  // RNE
    union { float f; u32 u; } v; v.f = f;
    u32 r = v.u + 0x7fffu + ((v.u >> 16) & 1u);
    return (u16)(r >> 16);
}
__device__ inline u32 pack2(float a, float b) {
    return (u32)f2bf(a) | ((u32)f2bf(b) << 16);
}
__device__ inline float wave_sum(float v) {
    for (int off = 32; off; off >>= 1) v += __shfl_xor(v, off, 64);
    return v;
}

// ---------- K1: normalize vis_global (fp32 + bf16), zero loss ----------
__global__ __launch_bounds__(256) void prep_vis(const float* __restrict__ vis,
                                                float* __restrict__ vis_n,
                                                u16* __restrict__ vis_nb,
                                                float* __restrict__ loss0)
{
    if (blockIdx.x == 0 && threadIdx.x == 0) loss0[0] = 0.0f;
    int wave = threadIdx.x >> 6, lane = threadIdx.x & 63;
    int b = blockIdx.x * 4 + wave;               // B = 512, grid 128
    const float* row = vis + b * 512 + lane * 8;
    float4 x0 = *(const float4*)row;
    float4 x1 = *(const float4*)(row + 4);
    float ss = x0.x*x0.x + x0.y*x0.y + x0.z*x0.z + x0.w*x0.w
             + x1.x*x1.x + x1.y*x1.y + x1.z*x1.z + x1.w*x1.w;
    ss = wave_sum(ss);
    float inv = 1.0f / fmaxf(sqrtf(ss), EPS);
    float4 y0, y1;
    y0.x = x0.x*inv; y0.y = x0.y*inv; y0.z = x0.z*inv; y0.w = x0.w*inv;
    y1.x = x1.x*inv; y1.y = x1.y*inv; y1.z = x1.z*inv; y1.w = x1.w*inv;
    *(float4*)(vis_n + b*512 + lane*8)     = y0;
    *(float4*)(vis_n + b*512 + lane*8 + 4) = y1;
    uint4 pk;
    pk.x = pack2(y0.x, y0.y); pk.y = pack2(y0.z, y0.w);
    pk.z = pack2(y1.x, y1.y); pk.w = pack2(y1.z, y1.w);
    *(uint4*)(vis_nb + b*512 + lane*8) = pk;
}

// ---------- K2: OUT[b0+r][j] = IN[b0+r]·W[j] + bias[j], 8 rows/block ----------
__global__ __launch_bounds__(256) void rowproj8(const float* __restrict__ IN,
                                                const float* __restrict__ W,
                                                const float* __restrict__ bias,
                                                float* __restrict__ OUT)
{
    __shared__ float sv[8 * 512];
    int t = threadIdx.x;
    int b0 = blockIdx.x * 8;
    const float4* src = (const float4*)(IN + b0 * 512);
    float4* dst4 = (float4*)sv;
    for (int i = t; i < 1024; i += 256) dst4[i] = src[i];
    __syncthreads();
    int j = blockIdx.y * 256 + t;                 // 512 outputs
    float acc[8];
    float bj = bias[j];
    for (int r = 0; r < 8; r++) acc[r] = bj;
    const float4* wr = (const float4*)(W + j * 512);
    for (int kk = 0; kk < 128; kk++) {
        float4 w = wr[kk];
        #pragma unroll
        for (int r = 0; r < 8; r++) {
            const float* vv = &sv[r * 512 + kk * 4];
            acc[r] += w.x*vv[0] + w.y*vv[1] + w.z*vv[2] + w.w*vv[3];
        }
    }
    for (int r = 0; r < 8; r++) OUT[(b0 + r) * 512 + j] = acc[r];
}

// ---------- K3: qk_all[b,h,j] = sum_d q[b, h*64+d] * wk[h*64+d, j] ----------
__global__ __launch_bounds__(256) void qk_proj(const float* __restrict__ q,
                                               const float* __restrict__ wk,
                                               float* __restrict__ qk_all)
{
    // grid (64, 8, 2)
    int bg = blockIdx.x, h = blockIdx.y;
    int t = threadIdx.x;
    int j = blockIdx.z * 256 + t;
    __shared__ float q8[8][64];
    {
        int r = t >> 5;            // 0..7
        int d0 = (t & 31) * 2;     // 0..62
        const float* qp = q + (bg * 8 + r) * 512 + h * 64 + d0;
        q8[r][d0] = qp[0]; q8[r][d0 + 1] = qp[1];
    }
    __syncthreads();
    float acc[8] = {0, 0, 0, 0, 0, 0, 0, 0};
    const float* wrow = wk + (size_t)(h * 64) * 512 + j;
    #pragma unroll 4
    for (int d = 0; d < 64; d++) {
        float w = wrow[(size_t)d * 512];
        #pragma unroll
        for (int r = 0; r < 8; r++) acc[r] += q8[r][d] * w;
    }
    #pragma unroll
    for (int r = 0; r < 8; r++)
        qk_all[((size_t)(bg * 8 + r) * 8 + h) * 512 + j] = acc[r];
}

// ---------- K4: fused sims+cluster+attention-core, one block per b ----------
// scores[h,m] = (X_b[m]·qk[h])/8 ; e=exp(s) ; u[h]=Σ e·X_m ; l[h]=Σ e
// u_all[b,h,:] = u/l  (softmax·X).  Also sims→cluster_scores inline.
__global__ __launch_bounds__(256) void fused_attn(const float* __restrict__ tf,
                                                  const float* __restrict__ vis_n,
                                                  const float* __restrict__ qk_all,
                                                  float* __restrict__ u_all,
                                                  float* __restrict__ out_cs)
{
    int b = blockIdx.x;
    int t = threadIdx.x, w = t >> 6, lane = t & 63;
    __shared__ float red[2 * 4096];   // 32 KB reduce buffer
    __shared__ float sm[96], srt[96];
    __shared__ float lred[4][8];

    float vn[8];
    {
        const float4* v4 = (const float4*)(vis_n + b * 512 + lane * 8);
        float4 a = v4[0], c = v4[1];
        vn[0]=a.x; vn[1]=a.y; vn[2]=a.z; vn[3]=a.w;
        vn[4]=c.x; vn[5]=c.y; vn[6]=c.z; vn[7]=c.w;
    }
    float qk[8][8];
    #pragma unroll
    for (int h = 0; h < 8; h++) {
        const float4* q4 = (const float4*)(qk_all + ((size_t)b * 8 + h) * 512 + lane * 8);
        float4 a = q4[0], c = q4[1];
        qk[h][0]=a.x; qk[h][1]=a.y; qk[h][2]=a.z; qk[h][3]=a.w;
        qk[h][4]=c.x; qk[h][5]=c.y; qk[h][6]=c.z; qk[h][7]=c.w;
    }
    float u[8][8];
    #pragma unroll
    for (int h = 0; h < 8; h++)
        #pragma unroll
        for (int j = 0; j < 8; j++) u[h][j] = 0.f;
    float l[8] = {0,0,0,0,0,0,0,0};

    for (int m = w; m < 96; m += 4) {
        const float4* x4 = (const float4*)(tf + ((size_t)b * 96 + m) * 512 + lane * 8);
        float4 a = x4[0], c = x4[1];
        float x[8] = {a.x, a.y, a.z, a.w, c.x, c.y, c.z, c.w};
        float ss = 0.f, dt = 0.f;
        float sh[8] = {0,0,0,0,0,0,0,0};
        #pragma unroll
        for (int j = 0; j < 8; j++) {
            ss += x[j] * x[j];
            dt += x[j] * vn[j];
            #pragma unroll
            for (int h = 0; h < 8; h++) sh[h] += x[j] * qk[h][j];
        }
        ss = wave_sum(ss);
        dt = wave_sum(dt);
        #pragma unroll
        for (int h = 0; h < 8; h++) sh[h] = wave_sum(sh[h]);
        if (lane == 0) sm[m] = dt / fmaxf(sqrtf(ss), EPS);
        #pragma unroll
        for (int h = 0; h < 8; h++) {
            float e = __expf(sh[h] * 0.125f);
            l[h] += e;
            #pragma unroll
            for (int j = 0; j < 8; j++) u[h][j] += e * x[j];
        }
    }
    // cross-wave reduce: waves 2,3 dump; 0,1 add; wave1 dumps; wave0 adds.
    if (w >= 2) {
        float* dst = red + (w - 2) * 4096;
        #pragma unroll
        for (int h = 0; h < 8; h++) {
            float4 p0, p1;
            p0.x=u[h][0]; p0.y=u[h][1]; p0.z=u[h][2]; p0.w=u[h][3];
            p1.x=u[h][4]; p1.y=u[h][5]; p1.z=u[h][6]; p1.w=u[h][7];
            *(float4*)&dst[h * 512 + lane * 8]     = p0;
            *(float4*)&dst[h * 512 + lane * 8 + 4] = p1;
        }
    }
    if (lane == 0) {
        #pragma unroll
        for (int h = 0; h < 8; h++) lred[w][h] = l[h];
    }
    __syncthreads();
    if (w < 2) {
        const float* src = red + w * 4096;
        #pragma unroll
        for (int h = 0; h < 8; h++) {
            float4 p0 = *(const float4*)&src[h * 512 + lane * 8];
            float4 p1 = *(const float4*)&src[h * 512 + lane * 8 + 4];
            u[h][0]+=p0.x; u[h][1]+=p0.y; u[h][2]+=p0.z; u[h][3]+=p0.w;
            u[h][4]+=p1.x; u[h][5]+=p1.y; u[h][6]+=p1.z; u[h][7]+=p1.w;
        }
    }
    __syncthreads();
    if (w == 1) {
        float* dst = red;
        #pragma unroll
        for (int h = 0; h < 8; h++) {
            float4 p0, p1;
            p0.x=u[h][0]; p0.y=u[h][1]; p0.z=u[h][2]; p0.w=u[h][3];
            p1.x=u[h][4]; p1.y=u[h][5]; p1.z=u[h][6]; p1.w=u[h][7];
            *(float4*)&dst[h * 512 + lane * 8]     = p0;
            *(float4*)&dst[h * 512 + lane * 8 + 4] = p1;
        }
    }
    __syncthreads();
    if (w == 0) {
        #pragma unroll
        for (int h = 0; h < 8; h++) {
            float lt = lred[0][h] + lred[1][h] + lred[2][h] + lred[3][h];
            float inv = 1.0f / lt;
            float4 p0 = *(const float4*)&red[h * 512 + lane * 8];
            float4 p1 = *(const float4*)&red[h * 512 + lane * 8 + 4];
            float4 o0, o1;
            o0.x = (u[h][0] + p0.x) * inv; o0.y = (u[h][1] + p0.y) * inv;
            o0.z = (u[h][2] + p0.z) * inv; o0.w = (u[h][3] + p0.w) * inv;
            o1.x = (u[h][4] + p1.x) * inv; o1.y = (u[h][5] + p1.y) * inv;
            o1.z = (u[h][6] + p1.z) * inv; o1.w = (u[h][7] + p1.w) * inv;
            *(float4*)(u_all + ((size_t)b * 8 + h) * 512 + lane * 8)     = o0;
            *(float4*)(u_all + ((size_t)b * 8 + h) * 512 + lane * 8 + 4) = o1;
        }
    }
    // cluster scores from sm (written before first sync)
    if (t < 96) {
        float v = sm[t]; int r = 0;
        for (int j2 = 0; j2 < 96; j2++) {
            float uq = sm[j2];
            r += (uq > v) || (uq == v && j2 < t);
        }
        srt[r] = v;
    }
    __syncthreads();
    if (t < 3) {
        float mean = 0.f;
        #pragma unroll 8
        for (int i = 0; i < 32; i++) mean += srt[t * 32 + i];
        mean *= (1.0f / 32.0f);
        float var = 0.f;
        #pragma unroll 8
        for (int i = 0; i < 32; i++) { float d = srt[t * 32 + i] - mean; var += d * d; }
        var *= (1.0f / 31.0f);
        out_cs[b * 3 + t] = mean / (sqrtf(var) + 1e-6f);
    }
}

// ---------- K5: ctx[b, h*64+d] = u_all[b,h,:]·wv[h*64+d,:] + bv[h*64+d] ----------
__global__ __launch_bounds__(256) void headproj(const float* __restrict__ u_all,
                                                const float* __restrict__ wv,
                                                const float* __restrict__ bv,
                                                float* __restrict__ ctx)
{
    // grid (64, 8)
    int bg = blockIdx.x, h = blockIdx.y, t = threadIdx.x;
    __shared__ float u8[8][512];
    {
        int r = t >> 5;              // 0..7
        int c = (t & 31) * 16;       // 16 floats per thread
        const float4* src = (const float4*)(u_all + ((size_t)(bg * 8 + r) * 8 + h) * 512 + c);
        float4* dst = (float4*)&u8[r][c];
        dst[0] = src[0]; dst[1] = src[1]; dst[2] = src[2]; dst[3] = src[3];
    }
    __syncthreads();
    int d = t & 63, rr = t >> 6;     // rr 0..3, handles b-rows rr and rr+4
    float acc0 = 0.f, acc1 = 0.f;
    const float4* w4 = (const float4*)(wv + (size_t)(h * 64 + d) * 512);
    const float4* ua = (const float4*)&u8[rr][0];
    const float4* ub = (const float4*)&u8[rr + 4][0];
    #pragma unroll 4
    for (int jj = 0; jj < 128; jj++) {
        float4 wv4 = w4[jj], a = ua[jj], b2 = ub[jj];
        acc0 += wv4.x*a.x + wv4.y*a.y + wv4.z*a.z + wv4.w*a.w;
        acc1 += wv4.x*b2.x + wv4.y*b2.y + wv4.z*b2.z + wv4.w*b2.w;
    }
    float bb = bv[h * 64 + d];
    ctx[(size_t)(bg * 8 + rr) * 512 + h * 64 + d]     = acc0 + bb;
    ctx[(size_t)(bg * 8 + rr + 4) * 512 + h * 64 + d] = acc1 + bb;
}

// ---------- K6: build normalized negatives (bf16) + pos_sim ----------
__global__ __launch_bounds__(256) void negs_build(const float* __restrict__ corrected,
                                                  const float* __restrict__ tm,
                                                  const float* __restrict__ vis_n,
                                                  u16* __restrict__ negs_nb,
                                                  float* __restrict__ pos)
{
    int wave = threadIdx.x >> 6, lane = threadIdx.x & 63;
    int j = blockIdx.x * 4 + wave;               // 0..1023, grid 256
    const float* src = (j < 512) ? (corrected + j * 512) : (tm + j * 512);
    const float* row = src + lane * 8;
    float4 x0 = *(const float4*)row;
    float4 x1 = *(const float4*)(row + 4);
    float ss = x0.x*x0.x + x0.y*x0.y + x0.z*x0.z + x0.w*x0.w
             + x1.x*x1.x + x1.y*x1.y + x1.z*x1.z + x1.w*x1.w;
    float dt = 0.f;
    if (j < 512) {
        const float* vn = vis_n + j * 512 + lane * 8;
        float4 v0 = *(const float4*)vn;
        float4 v1 = *(const float4*)(vn + 4);
        dt = x0.x*v0.x + x0.y*v0.y + x0.z*v0.z + x0.w*v0.w
           + x1.x*v1.x + x1.y*v1.y + x1.z*v1.z + x1.w*v1.w;
    }
    ss = wave_sum(ss);
    dt = wave_sum(dt);
    float inv = 1.0f / fmaxf(sqrtf(ss), EPS);
    float4 y0, y1;
    y0.x = x0.x*inv; y0.y = x0.y*inv; y0.z = x0.z*inv; y0.w = x0.w*inv;
    y1.x = x1.x*inv; y1.y = x1.y*inv; y1.z = x1.z*inv; y1.w = x1.w*inv;
    uint4 pk;
    pk.x = pack2(y0.x, y0.y); pk.y = pack2(y0.z, y0.w);
    pk.z = pack2(y1.x, y1.y); pk.w = pack2(y1.z, y1.w);
    *(uint4*)(negs_nb + j * 512 + lane * 8) = pk;
    if (j < 512 && lane == 0) pos[j] = dt * inv;
}

// ---------- K7: C = A(Mx512) @ Bm(Nx512)^T  (bf16 MFMA 16x16x32), fp32 out ----------
__global__ __launch_bounds__(256) void gemm_bt(const u16* __restrict__ A,
                                               const u16* __restrict__ Bm,
                                               float* __restrict__ Cf)
{
    __shared__ __align__(16) u16 As[128 * 64];
    __shared__ __align__(16) u16 Bs[128 * 64];
    const int t = threadIdx.x;
    const int lane = t & 63;
    const int wave = t >> 6;
    const int m0 = blockIdx.x * 128;
    const int n0 = blockIdx.y * 128;
    const int wm = (wave >> 1) * 64;
    const int wn = (wave & 1) * 64;
    const int l16 = lane & 15, quad = lane >> 4;
    const int srow = t >> 3;            // 0..31
    const int scol = (t & 7) * 8;       // 0..56 elements

    f32x4 acc[4][4];
    for (int i = 0; i < 4; i++)
        for (int j = 0; j < 4; j++)
            for (int e = 0; e < 4; e++) acc[i][j][e] = 0.f;

    for (int ko = 0; ko < 512; ko += 64) {
        __syncthreads();
        #pragma unroll
        for (int i = 0; i < 4; i++) {
            int row = i * 32 + srow;
            *(uint4*)&As[row * 64 + scol] = *(const uint4*)&A[(m0 + row) * 512 + ko + scol];
            *(uint4*)&Bs[row * 64 + scol] = *(const uint4*)&Bm[(n0 + row) * 512 + ko + scol];
        }
        __syncthreads();
        #pragma unroll
        for (int ks = 0; ks < 2; ks++) {
            short8 af[4], bfr[4];
            #pragma unroll
            for (int i = 0; i < 4; i++)
                af[i] = *(const short8*)&As[(wm + i * 16 + l16) * 64 + ks * 32 + quad * 8];
            #pragma unroll
            for (int j = 0; j < 4; j++)
                bfr[j] = *(const short8*)&Bs[(wn + j * 16 + l16) * 64 + ks * 32 + quad * 8];
            #pragma unroll
            for (int i = 0; i < 4; i++)
                #pragma unroll
                for (int j = 0; j < 4; j++)
                    acc[i][j] = __builtin_amdgcn_mfma_f32_16x16x32_bf16(af[i], bfr[j], acc[i][j], 0, 0, 0);
        }
    }
    for (int i = 0; i < 4; i++) {
        int row = m0 + wm + i * 16 + quad * 4;
        for (int j = 0; j < 4; j++) {
            int col = n0 + wn + j * 16 + l16;
            for (int r = 0; r < 4; r++)
                Cf[(size_t)(row + r) * 1024 + col] = acc[i][j][r];
        }
    }
}

// ---------- K8: top-5 over 1536-multiset + loss ----------
__global__ __launch_bounds__(256) void topk_loss(const float* __restrict__ ns,
                                                 const float* __restrict__ pos,
                                                 const float* __restrict__ tau_p_log,
                                                 const float* __restrict__ tau_n_log,
                                                 float* __restrict__ out_loss)
{
    int b = blockIdx.x, t = threadIdx.x;
    __shared__ float sv[1536];
    __shared__ float rv[256];
    __shared__ int   ri[256];
    __shared__ float stop5[5];
    const float* row = ns + b * 1024;
    for (int i = t; i < 1536; i += 256) {
        float v;
        if (i < 1024) v = row[i & 511];          // corr sims appear twice (roll + mem)
        else          v = row[512 + (i - 1024)]; // memory sims
        sv[i] = v;
    }
    __syncthreads();
    for (int r = 0; r < 5; r++) {
        float best = -1e30f; int bi = 0;
        for (int i = t; i < 1536; i += 256)
            if (sv[i] > best) { best = sv[i]; bi = i; }
        rv[t] = best; ri[t] = bi;
        __syncthreads();
        for (int s = 128; s > 0; s >>= 1) {
            if (t < s) {
                if (rv[t + s] > rv[t]) { rv[t] = rv[t + s]; ri[t] = ri[t + s]; }
            }
            __syncthreads();
        }
        if (t == 0) { stop5[r] = rv[0]; sv[ri[0]] = -1e30f; }
        __syncthreads();
    }
    if (t == 0) {
        float tp = expf(tau_p_log[0]), tn = expf(tau_n_log[0]);
        float p = expf(pos[b] / tp);
        float n = 0.f;
        for (int r = 0; r < 5; r++) n += expf(stop5[r] / tn);
        float term = logf(p / (p + n + 1e-8f));
        atomicAdd(out_loss, -term * (1.0f / 512.0f));
    }
}

// ---------- launch ----------
extern "C" void kernel_launch(void* const* d_in, const int* in_sizes, int n_in,
                              void* d_out, int out_size, void* d_ws, size_t ws_size,
                              hipStream_t stream) {
    const float* vis = (const float*)d_in[0];
    const float* tf  = (const float*)d_in[1];
    const float* ipw = (const float*)d_in[2];
    const float* ipb = (const float*)d_in[3];
    const float* opw = (const float*)d_in[4];
    const float* opb = (const float*)d_in[5];
    const float* tm  = (const float*)d_in[6];
    const float* tpl = (const float*)d_in[7];
    const float* tnl = (const float*)d_in[8];

    float* out       = (float*)d_out;
    float* out_loss  = out;
    float* out_corr  = out + 1;                  // (512,512)
    float* out_cs    = out + 1 + 512 * 512;      // (512,3)

    char* p = (char*)d_ws;
    auto alloc = [&](size_t bytes) { char* r = p; p += (bytes + 255) & ~(size_t)255; return r; };
    float* vis_n  = (float*)alloc(512 * 512 * 4);
    u16*   vis_nb = (u16*)  alloc(512 * 512 * 2);
    float* qws    = (float*)alloc(512 * 512 * 4);
    float* qk_all = (float*)alloc((size_t)512 * 8 * 512 * 4);
    float* u_all  = (float*)alloc((size_t)512 * 8 * 512 * 4);
    float* ctx    = (float*)alloc(512 * 512 * 4);
    u16*   negsb  = (u16*)  alloc(1024 * 512 * 2);
    float* ns     = (float*)alloc(512 * 1024 * 4);
    float* pos    = (float*)alloc(512 * 4);

    const float* wk = ipw + 512 * 512;           // rows 512..1023
    const float* wv = ipw + 2 * 512 * 512;       // rows 1024..1535
    const float* bv = ipb + 2 * 512;

    prep_vis<<<128, 256, 0, stream>>>(vis, vis_n, vis_nb, out_loss);
    rowproj8<<<dim3(64, 2), 256, 0, stream>>>(vis, ipw, ipb, qws);          // q
    qk_proj<<<dim3(64, 8, 2), 256, 0, stream>>>(qws, wk, qk_all);
    fused_attn<<<512, 256, 0, stream>>>(tf, vis_n, qk_all, u_all, out_cs);
    headproj<<<dim3(64, 8), 256, 0, stream>>>(u_all, wv, bv, ctx);
    rowproj8<<<dim3(64, 2), 256, 0, stream>>>(ctx, opw, opb, out_corr);     // corrected
    negs_build<<<256, 256, 0, stream>>>(out_corr, tm, vis_n, negsb, pos);
    gemm_bt<<<dim3(4, 8), 256, 0, stream>>>(vis_nb, negsb, ns);
    topk_loss<<<512, 256, 0, stream>>>(ns, pos, tpl, tnl, out_loss);
}

// Round 3
// 253.359 us; speedup vs baseline: 1.4518x; 1.2576x over previous
//
#include <hip/hip_runtime.h>
#include <math.h>

typedef unsigned short u16;
typedef unsigned int u32;
typedef __attribute__((ext_vector_type(8))) short short8;   // 8 bf16 (4 VGPRs) MFMA A/B frag
typedef __attribute__((ext_vector_type(4))) float f32x4;    // MFMA C/D frag

#define EPS 1e-8f

// ---------- helpers ----------
__device__ inline float bf2f(u16 u) {
    union { u32 i; float f; } v; v.i = ((u32)u) << 16; return v.f;
}
__device__ inline u16 f2bf(float f) {  // RNE
    union { float f; u32 u; } v; v.f = f;
    u32 r = v.u + 0x7fffu + ((v.u >> 16) & 1u);
    return (u16)(r >> 16);
}
__device__ inline u32 pack2(float a, float b) {
    return (u32)f2bf(a) | ((u32)f2bf(b) << 16);
}
__device__ inline float wave_sum(float v) {
    for (int off = 32; off; off >>= 1) v += __shfl_xor(v, off, 64);
    return v;
}

// ---------- K1: normalize vis_global (fp32 + bf16) + raw bf16 copy, zero loss ----------
__global__ __launch_bounds__(256) void prep_vis(const float* __restrict__ vis,
                                                float* __restrict__ vis_n,
                                                u16* __restrict__ vis_nb,
                                                u16* __restrict__ vis_b,
                                                float* __restrict__ loss0)
{
    if (blockIdx.x == 0 && threadIdx.x == 0) loss0[0] = 0.0f;
    int wave = threadIdx.x >> 6, lane = threadIdx.x & 63;
    int b = blockIdx.x * 4 + wave;               // B = 512, grid 128
    const float* row = vis + b * 512 + lane * 8;
    float4 x0 = *(const float4*)row;
    float4 x1 = *(const float4*)(row + 4);
    // raw bf16 copy (for q GEMM)
    uint4 rk;
    rk.x = pack2(x0.x, x0.y); rk.y = pack2(x0.z, x0.w);
    rk.z = pack2(x1.x, x1.y); rk.w = pack2(x1.z, x1.w);
    *(uint4*)(vis_b + b*512 + lane*8) = rk;
    float ss = x0.x*x0.x + x0.y*x0.y + x0.z*x0.z + x0.w*x0.w
             + x1.x*x1.x + x1.y*x1.y + x1.z*x1.z + x1.w*x1.w;
    ss = wave_sum(ss);
    float inv = 1.0f / fmaxf(sqrtf(ss), EPS);
    float4 y0, y1;
    y0.x = x0.x*inv; y0.y = x0.y*inv; y0.z = x0.z*inv; y0.w = x0.w*inv;
    y1.x = x1.x*inv; y1.y = x1.y*inv; y1.z = x1.z*inv; y1.w = x1.w*inv;
    *(float4*)(vis_n + b*512 + lane*8)     = y0;
    *(float4*)(vis_n + b*512 + lane*8 + 4) = y1;
    uint4 pk;
    pk.x = pack2(y0.x, y0.y); pk.y = pack2(y0.z, y0.w);
    pk.z = pack2(y1.x, y1.y); pk.w = pack2(y1.z, y1.w);
    *(uint4*)(vis_nb + b*512 + lane*8) = pk;
}

// ---------- K2: convert Wq, Wv, Wo to bf16 ----------
__global__ __launch_bounds__(256) void cvt3(const float* __restrict__ ipw,
                                            const float* __restrict__ opw,
                                            u16* __restrict__ wqb,
                                            u16* __restrict__ wvb,
                                            u16* __restrict__ wob)
{
    int i = (blockIdx.x * 256 + threadIdx.x) * 4;   // 786432 elems, grid 768
    const float* src; u16* dst; int j;
    if (i < 262144)      { j = i;          src = ipw + j;          dst = wqb + j; }
    else if (i < 524288) { j = i - 262144; src = ipw + 524288 + j; dst = wvb + j; }
    else                 { j = i - 524288; src = opw + j;          dst = wob + j; }
    float4 v = *(const float4*)src;
    uint2 pk; pk.x = pack2(v.x, v.y); pk.y = pack2(v.z, v.w);
    *(uint2*)dst = pk;
}

// ---------- K3/K7/K9: C(MxN) = A(Mx512,bf16) @ B(Nx512,bf16)^T [+bias], fp32 out ----------
// 64x64 tile, 256 threads (4 waves, each 32x32 = 2x2 frags)
__global__ __launch_bounds__(256) void gemm64(const u16* __restrict__ A, int lda,
                                              const u16* __restrict__ B,
                                              const float* __restrict__ bias,
                                              float* __restrict__ Cf, int ldc)
{
    __shared__ __align__(16) u16 As[64 * 64];
    __shared__ __align__(16) u16 Bs[64 * 64];
    const int t = threadIdx.x, lane = t & 63, w = t >> 6;
    const int m0 = blockIdx.x * 64, n0 = blockIdx.y * 64;
    const int wm = (w >> 1) * 32, wn = (w & 1) * 32;
    const int l16 = lane & 15, quad = lane >> 4;
    const int srow = t >> 3, scol = (t & 7) * 8;

    f32x4 acc[2][2];
    for (int i = 0; i < 2; i++)
        for (int j = 0; j < 2; j++)
            for (int e = 0; e < 4; e++) acc[i][j][e] = 0.f;

    for (int ko = 0; ko < 512; ko += 64) {
        __syncthreads();
        #pragma unroll
        for (int i = 0; i < 2; i++) {
            int row = i * 32 + srow;
            *(uint4*)&As[row * 64 + scol] = *(const uint4*)&A[(size_t)(m0 + row) * lda + ko + scol];
            *(uint4*)&Bs[row * 64 + scol] = *(const uint4*)&B[(size_t)(n0 + row) * 512 + ko + scol];
        }
        __syncthreads();
        #pragma unroll
        for (int ks = 0; ks < 2; ks++) {
            short8 af[2], bfr[2];
            #pragma unroll
            for (int i = 0; i < 2; i++)
                af[i] = *(const short8*)&As[(wm + i * 16 + l16) * 64 + ks * 32 + quad * 8];
            #pragma unroll
            for (int j = 0; j < 2; j++)
                bfr[j] = *(const short8*)&Bs[(wn + j * 16 + l16) * 64 + ks * 32 + quad * 8];
            #pragma unroll
            for (int i = 0; i < 2; i++)
                #pragma unroll
                for (int j = 0; j < 2; j++)
                    acc[i][j] = __builtin_amdgcn_mfma_f32_16x16x32_bf16(af[i], bfr[j], acc[i][j], 0, 0, 0);
        }
    }
    for (int i = 0; i < 2; i++) {
        int row = m0 + wm + i * 16 + quad * 4;
        for (int j = 0; j < 2; j++) {
            int col = n0 + wn + j * 16 + l16;
            float bv = bias ? bias[col] : 0.f;
            for (int r = 0; r < 4; r++)
                Cf[(size_t)(row + r) * ldc + col] = acc[i][j][r] + bv;
        }
    }
}

// ---------- K6: ctx_h(512x64) = u_h(512x512) @ Wv_h(64x512)^T + bv_h, bf16 out ----------
__global__ __launch_bounds__(256) void gemm_head(const u16* __restrict__ u_allb,
                                                 const u16* __restrict__ wvb,
                                                 const float* __restrict__ bv,
                                                 u16* __restrict__ ctxb)
{
    // grid (8 m-tiles, 8 heads)
    const int h = blockIdx.y;
    const u16* A = u_allb + h * 512;                 // lda 4096
    const u16* B = wvb + (size_t)h * 64 * 512;       // 64 rows, ldb 512
    __shared__ __align__(16) u16 As[64 * 64];
    __shared__ __align__(16) u16 Bs[64 * 64];
    const int t = threadIdx.x, lane = t & 63, w = t >> 6;
    const int m0 = blockIdx.x * 64;
    const int wm = (w >> 1) * 32, wn = (w & 1) * 32;
    const int l16 = lane & 15, quad = lane >> 4;
    const int srow = t >> 3, scol = (t & 7) * 8;

    f32x4 acc[2][2];
    for (int i = 0; i < 2; i++)
        for (int j = 0; j < 2; j++)
            for (int e = 0; e < 4; e++) acc[i][j][e] = 0.f;

    for (int ko = 0; ko < 512; ko += 64) {
        __syncthreads();
        #pragma unroll
        for (int i = 0; i < 2; i++) {
            int row = i * 32 + srow;
            *(uint4*)&As[row * 64 + scol] = *(const uint4*)&A[(size_t)(m0 + row) * 4096 + ko + scol];
            *(uint4*)&Bs[row * 64 + scol] = *(const uint4*)&B[(size_t)row * 512 + ko + scol];
        }
        __syncthreads();
        #pragma unroll
        for (int ks = 0; ks < 2; ks++) {
            short8 af[2], bfr[2];
            #pragma unroll
            for (int i = 0; i < 2; i++)
                af[i] = *(const short8*)&As[(wm + i * 16 + l16) * 64 + ks * 32 + quad * 8];
            #pragma unroll
            for (int j = 0; j < 2; j++)
                bfr[j] = *(const short8*)&Bs[(wn + j * 16 + l16) * 64 + ks * 32 + quad * 8];
            #pragma unroll
            for (int i = 0; i < 2; i++)
                #pragma unroll
                for (int j = 0; j < 2; j++)
                    acc[i][j] = __builtin_amdgcn_mfma_f32_16x16x32_bf16(af[i], bfr[j], acc[i][j], 0, 0, 0);
        }
    }
    for (int i = 0; i < 2; i++) {
        int row = m0 + wm + i * 16 + quad * 4;
        for (int j = 0; j < 2; j++) {
            int col = wn + j * 16 + l16;             // 0..63 within head
            float bb = bv[h * 64 + col];
            for (int r = 0; r < 4; r++)
                ctxb[(size_t)(row + r) * 512 + h * 64 + col] = f2bf(acc[i][j][r] + bb);
        }
    }
}

// ---------- K4: qk_all[b,h,j] = sum_d q[b,h*64+d] * wk[h*64+d, j]  (fp32) ----------
__global__ __launch_bounds__(256) void qk_proj(const float* __restrict__ q,
                                               const float* __restrict__ wk,
                                               float* __restrict__ qk_all)
{
    // grid (64, 8, 2)
    int bg = blockIdx.x, h = blockIdx.y;
    int t = threadIdx.x;
    int j = blockIdx.z * 256 + t;
    __shared__ float q8[8][64];
    {
        int r = t >> 5;            // 0..7
        int d0 = (t & 31) * 2;     // 0..62
        const float* qp = q + (bg * 8 + r) * 512 + h * 64 + d0;
        q8[r][d0] = qp[0]; q8[r][d0 + 1] = qp[1];
    }
    __syncthreads();
    float acc[8] = {0, 0, 0, 0, 0, 0, 0, 0};
    const float* wrow = wk + (size_t)(h * 64) * 512 + j;
    #pragma unroll 4
    for (int d = 0; d < 64; d++) {
        float ww = wrow[(size_t)d * 512];
        #pragma unroll
        for (int r = 0; r < 8; r++) acc[r] += q8[r][d] * ww;
    }
    #pragma unroll
    for (int r = 0; r < 8; r++)
        qk_all[((size_t)(bg * 8 + r) * 8 + h) * 512 + j] = acc[r];
}

// ---------- K5: fused sims+cluster+attention via LDS-resident MFMA, 1 block/b ----------
__global__ __launch_bounds__(512) void fused_attn(const float* __restrict__ tf,
                                                  const float* __restrict__ vis_n,
                                                  const float* __restrict__ qk_all,
                                                  u16* __restrict__ u_allb,
                                                  float* __restrict__ out_cs)
{
    __shared__ __align__(16) u16 Xs[96 * 520];    // 99840 B, bf16 X_b (pad 8)
    __shared__ __align__(16) u16 Qs[16 * 520];    // 16640 B, bf16 qk (rows 8..15 unused)
    __shared__ __align__(16) u16 Ps[16 * 104];    //  3328 B, bf16 exp(scores)
    __shared__ float Sc[16 * 100];                //  6400 B, scores [h][m]
    __shared__ float sm_[96], srt[96], linv[8];

    const int b = blockIdx.x;
    const int t = threadIdx.x, w = t >> 6, lane = t & 63;
    const int l16 = lane & 15, quad = lane >> 4;

    // vis_n row (for sims)
    const float4* v4 = (const float4*)(vis_n + b * 512 + lane * 8);
    float4 va = v4[0], vb = v4[1];

    // stage Qs row w (fp32 -> bf16); wave w owns head w
    {
        const float4* q4 = (const float4*)(qk_all + ((size_t)b * 8 + w) * 512 + lane * 8);
        float4 a = q4[0], c = q4[1];
        uint4 pk;
        pk.x = pack2(a.x, a.y); pk.y = pack2(a.z, a.w);
        pk.z = pack2(c.x, c.y); pk.w = pack2(c.z, c.w);
        *(uint4*)&Qs[w * 520 + lane * 8] = pk;
    }

    // stage Xs (bf16) + sims; wave w handles rows m = w + 8i
    #pragma unroll 2
    for (int i = 0; i < 12; i++) {
        int m = w + i * 8;
        const float4* x4 = (const float4*)(tf + ((size_t)b * 96 + m) * 512 + lane * 8);
        float4 a = x4[0], c = x4[1];
        float ss = a.x*a.x + a.y*a.y + a.z*a.z + a.w*a.w
                 + c.x*c.x + c.y*c.y + c.z*c.z + c.w*c.w;
        float dt = a.x*va.x + a.y*va.y + a.z*va.z + a.w*va.w
                 + c.x*vb.x + c.y*vb.y + c.z*vb.z + c.w*vb.w;
        ss = wave_sum(ss);
        dt = wave_sum(dt);
        if (lane == 0) sm_[m] = dt / fmaxf(sqrtf(ss), EPS);
        uint4 pk;
        pk.x = pack2(a.x, a.y); pk.y = pack2(a.z, a.w);
        pk.z = pack2(c.x, c.y); pk.w = pack2(c.z, c.w);
        *(uint4*)&Xs[m * 520 + lane * 8] = pk;
    }
    __syncthreads();

    // scores: C[m][h] = X @ qk^T / 8 ; waves 0..5 take m-tiles
    if (w < 6) {
        f32x4 acc;
        for (int e = 0; e < 4; e++) acc[e] = 0.f;
        #pragma unroll
        for (int ks = 0; ks < 16; ks++) {
            short8 a = *(const short8*)&Xs[(w * 16 + l16) * 520 + ks * 32 + quad * 8];
            short8 q = *(const short8*)&Qs[l16 * 520 + ks * 32 + quad * 8];
            acc = __builtin_amdgcn_mfma_f32_16x16x32_bf16(a, q, acc, 0, 0, 0);
        }
        #pragma unroll
        for (int r = 0; r < 4; r++)
            Sc[l16 * 100 + w * 16 + quad * 4 + r] = acc[r] * 0.125f;   // h=l16, m=w*16+quad*4+r
    }
    __syncthreads();

    // softmax (wave w = head w) -> Ps (unnormalized exp, bf16) + linv
    {
        float e0 = __expf(Sc[w * 100 + lane]);
        float e1 = (lane < 32) ? __expf(Sc[w * 100 + 64 + lane]) : 0.f;
        float l = wave_sum(e0 + e1);
        Ps[w * 104 + lane] = f2bf(e0);
        if (lane < 32) Ps[w * 104 + 64 + lane] = f2bf(e1);
        if (lane == 0) linv[w] = 1.0f / l;
    }
    // cluster rank (sims from phase 1)
    if (t < 96) {
        float v = sm_[t]; int r = 0;
        for (int j = 0; j < 96; j++) {
            float u = sm_[j];
            r += (u > v) || (u == v && j < t);
        }
        srt[r] = v;
    }
    __syncthreads();

    // u GEMM: C[h][d] = P(8x96) @ X(96x512); wave w takes n-tiles w*4..w*4+3
    #pragma unroll
    for (int jj = 0; jj < 4; jj++) {
        int n0 = (w * 4 + jj) * 16;
        f32x4 acc;
        for (int e = 0; e < 4; e++) acc[e] = 0.f;
        #pragma unroll
        for (int ks = 0; ks < 3; ks++) {
            short8 ap = *(const short8*)&Ps[l16 * 104 + ks * 32 + quad * 8];
            short8 bx;
            #pragma unroll
            for (int j = 0; j < 8; j++)
                bx[j] = (short)Xs[(ks * 32 + quad * 8 + j) * 520 + n0 + l16];
            acc = __builtin_amdgcn_mfma_f32_16x16x32_bf16(ap, bx, acc, 0, 0, 0);
        }
        if (quad < 2) {
            #pragma unroll
            for (int r = 0; r < 4; r++) {
                int h = quad * 4 + r;
                u_allb[((size_t)b * 8 + h) * 512 + n0 + l16] = f2bf(acc[r] * linv[h]);
            }
        }
    }
    // cluster stats
    if (t < 3) {
        float mean = 0.f;
        #pragma unroll 8
        for (int i = 0; i < 32; i++) mean += srt[t * 32 + i];
        mean *= (1.0f / 32.0f);
        float var = 0.f;
        #pragma unroll 8
        for (int i = 0; i < 32; i++) { float d = srt[t * 32 + i] - mean; var += d * d; }
        var *= (1.0f / 31.0f);
        out_cs[b * 3 + t] = mean / (sqrtf(var) + 1e-6f);
    }
}

// ---------- K8: build normalized negatives (bf16) + pos_sim ----------
__global__ __launch_bounds__(256) void negs_build(const float* __restrict__ corrected,
                                                  const float* __restrict__ tm,
                                                  const float* __restrict__ vis_n,
                                                  u16* __restrict__ negs_nb,
                                                  float* __restrict__ pos)
{
    int wave = threadIdx.x >> 6, lane = threadIdx.x & 63;
    int j = blockIdx.x * 4 + wave;               // 0..1023, grid 256
    const float* src = (j < 512) ? (corrected + j * 512) : (tm + j * 512);
    const float* row = src + lane * 8;
    float4 x0 = *(const float4*)row;
    float4 x1 = *(const float4*)(row + 4);
    float ss = x0.x*x0.x + x0.y*x0.y + x0.z*x0.z + x0.w*x0.w
             + x1.x*x1.x + x1.y*x1.y + x1.z*x1.z + x1.w*x1.w;
    float dt = 0.f;
    if (j < 512) {
        const float* vn = vis_n + j * 512 + lane * 8;
        float4 v0 = *(const float4*)vn;
        float4 v1 = *(const float4*)(vn + 4);
        dt = x0.x*v0.x + x0.y*v0.y + x0.z*v0.z + x0.w*v0.w
           + x1.x*v1.x + x1.y*v1.y + x1.z*v1.z + x1.w*v1.w;
    }
    ss = wave_sum(ss);
    dt = wave_sum(dt);
    float inv = 1.0f / fmaxf(sqrtf(ss), EPS);
    float4 y0, y1;
    y0.x = x0.x*inv; y0.y = x0.y*inv; y0.z = x0.z*inv; y0.w = x0.w*inv;
    y1.x = x1.x*inv; y1.y = x1.y*inv; y1.z = x1.z*inv; y1.w = x1.w*inv;
    uint4 pk;
    pk.x = pack2(y0.x, y0.y); pk.y = pack2(y0.z, y0.w);
    pk.z = pack2(y1.x, y1.y); pk.w = pack2(y1.z, y1.w);
    *(uint4*)(negs_nb + j * 512 + lane * 8) = pk;
    if (j < 512 && lane == 0) pos[j] = dt * inv;
}

// ---------- K10: top-5 over 1536-multiset + loss ----------
__global__ __launch_bounds__(256) void topk_loss(const float* __restrict__ ns,
                                                 const float* __restrict__ pos,
                                                 const float* __restrict__ tau_p_log,
                                                 const float* __restrict__ tau_n_log,
                                                 float* __restrict__ out_loss)
{
    int b = blockIdx.x, t = threadIdx.x;
    __shared__ float sv[1536];
    __shared__ float rv[256];
    __shared__ int   ri[256];
    __shared__ float stop5[5];
    const float* row = ns + b * 1024;
    for (int i = t; i < 1536; i += 256) {
        float v;
        if (i < 1024) v = row[i & 511];          // corr sims appear twice (roll + mem)
        else          v = row[512 + (i - 1024)]; // memory sims
        sv[i] = v;
    }
    __syncthreads();
    for (int r = 0; r < 5; r++) {
        float best = -1e30f; int bi = 0;
        for (int i = t; i < 1536; i += 256)
            if (sv[i] > best) { best = sv[i]; bi = i; }
        rv[t] = best; ri[t] = bi;
        __syncthreads();
        for (int s = 128; s > 0; s >>= 1) {
            if (t < s) {
                if (rv[t + s] > rv[t]) { rv[t] = rv[t + s]; ri[t] = ri[t + s]; }
            }
            __syncthreads();
        }
        if (t == 0) { stop5[r] = rv[0]; sv[ri[0]] = -1e30f; }
        __syncthreads();
    }
    if (t == 0) {
        float tp = expf(tau_p_log[0]), tn = expf(tau_n_log[0]);
        float p = expf(pos[b] / tp);
        float n = 0.f;
        for (int r = 0; r < 5; r++) n += expf(stop5[r] / tn);
        float term = logf(p / (p + n + 1e-8f));
        atomicAdd(out_loss, -term * (1.0f / 512.0f));
    }
}

// ---------- launch ----------
extern "C" void kernel_launch(void* const* d_in, const int* in_sizes, int n_in,
                              void* d_out, int out_size, void* d_ws, size_t ws_size,
                              hipStream_t stream) {
    const float* vis = (const float*)d_in[0];
    const float* tf  = (const float*)d_in[1];
    const float* ipw = (const float*)d_in[2];
    const float* ipb = (const float*)d_in[3];
    const float* opw = (const float*)d_in[4];
    const float* opb = (const float*)d_in[5];
    const float* tm  = (const float*)d_in[6];
    const float* tpl = (const float*)d_in[7];
    const float* tnl = (const float*)d_in[8];

    float* out       = (float*)d_out;
    float* out_loss  = out;
    float* out_corr  = out + 1;                  // (512,512)
    float* out_cs    = out + 1 + 512 * 512;      // (512,3)

    char* p = (char*)d_ws;
    auto alloc = [&](size_t bytes) { char* r = p; p += (bytes + 255) & ~(size_t)255; return r; };
    float* vis_n  = (float*)alloc(512 * 512 * 4);
    u16*   vis_nb = (u16*)  alloc(512 * 512 * 2);
    u16*   vis_b  = (u16*)  alloc(512 * 512 * 2);
    u16*   wqb    = (u16*)  alloc(512 * 512 * 2);
    u16*   wvb    = (u16*)  alloc(512 * 512 * 2);
    u16*   wob    = (u16*)  alloc(512 * 512 * 2);
    float* qws    = (float*)alloc(512 * 512 * 4);
    float* qk_all = (float*)alloc((size_t)512 * 8 * 512 * 4);
    u16*   u_allb = (u16*)  alloc((size_t)512 * 8 * 512 * 2);
    u16*   ctxb   = (u16*)  alloc(512 * 512 * 2);
    u16*   negsb  = (u16*)  alloc(1024 * 512 * 2);
    float* ns     = (float*)alloc(512 * 1024 * 4);
    float* pos    = (float*)alloc(512 * 4);

    const float* wk = ipw + 512 * 512;           // fp32 rows 512..1023
    const float* bv = ipb + 2 * 512;

    prep_vis<<<128, 256, 0, stream>>>(vis, vis_n, vis_nb, vis_b, out_loss);
    cvt3<<<768, 256, 0, stream>>>(ipw, opw, wqb, wvb, wob);
    gemm64<<<dim3(8, 8), 256, 0, stream>>>(vis_b, 512, wqb, ipb, qws, 512);        // q
    qk_proj<<<dim3(64, 8, 2), 256, 0, stream>>>(qws, wk, qk_all);
    fused_attn<<<512, 512, 0, stream>>>(tf, vis_n, qk_all, u_allb, out_cs);
    gemm_head<<<dim3(8, 8), 256, 0, stream>>>(u_allb, wvb, bv, ctxb);              // ctx (bf16)
    gemm64<<<dim3(8, 8), 256, 0, stream>>>(ctxb, 512, wob, opb, out_corr, 512);    // corrected
    negs_build<<<256, 256, 0, stream>>>(out_corr, tm, vis_n, negsb, pos);
    gemm64<<<dim3(8, 16), 256, 0, stream>>>(vis_nb, 512, negsb, nullptr, ns, 1024);
    topk_loss<<<512, 256, 0, stream>>>(ns, pos, tpl, tnl, out_loss);
}

// Round 4
// 250.526 us; speedup vs baseline: 1.4682x; 1.0113x over previous
//
#include <hip/hip_runtime.h>
#include <math.h>

typedef unsigned short u16;
typedef unsigned int u32;
typedef __attribute__((ext_vector_type(8))) short short8;   // 8 bf16 (4 VGPRs) MFMA A/B frag
typedef __attribute__((ext_vector_type(4))) float f32x4;    // MFMA C/D frag

#define EPS 1e-8f

// ---------- helpers ----------
__device__ inline float bf2f(u16 u) {
    union { u32 i; float f; } v; v.i = ((u32)u) << 16; return v.f;
}
__device__ inline u16 f2bf(float f) {  // RNE
    union { float f; u32 u; } v; v.f = f;
    u32 r = v.u + 0x7fffu + ((v.u >> 16) & 1u);
    return (u16)(r >> 16);
}
__device__ inline u32 pack2(float a, float b) {
    return (u32)f2bf(a) | ((u32)f2bf(b) << 16);
}
__device__ inline float wave_sum(float v) {
    for (int off = 32; off; off >>= 1) v += __shfl_xor(v, off, 64);
    return v;
}

// ---------- K1: prep = vis normalize (fp32+bf16) + raw bf16 + Wq/Wv/Wo cvt ----------
__global__ __launch_bounds__(256) void prep(const float* __restrict__ vis,
                                            const float* __restrict__ ipw,
                                            const float* __restrict__ opw,
                                            float* __restrict__ vis_n,
                                            u16* __restrict__ vis_nb,
                                            u16* __restrict__ vis_b,
                                            u16* __restrict__ wqb,
                                            u16* __restrict__ wvb,
                                            u16* __restrict__ wob,
                                            float* __restrict__ loss0)
{
    int bid = blockIdx.x;
    if (bid >= 128) {
        // weight conversion part (768 blocks)
        int i = ((bid - 128) * 256 + threadIdx.x) * 4;   // 786432 elems
        const float* src; u16* dst; int j;
        if (i < 262144)      { j = i;          src = ipw + j;          dst = wqb + j; }
        else if (i < 524288) { j = i - 262144; src = ipw + 524288 + j; dst = wvb + j; }
        else                 { j = i - 524288; src = opw + j;          dst = wob + j; }
        float4 v = *(const float4*)src;
        uint2 pk; pk.x = pack2(v.x, v.y); pk.y = pack2(v.z, v.w);
        *(uint2*)dst = pk;
        return;
    }
    if (bid == 0 && threadIdx.x == 0) loss0[0] = 0.0f;
    int wave = threadIdx.x >> 6, lane = threadIdx.x & 63;
    int b = bid * 4 + wave;                      // B = 512
    const float* row = vis + b * 512 + lane * 8;
    float4 x0 = *(const float4*)row;
    float4 x1 = *(const float4*)(row + 4);
    uint4 rk;
    rk.x = pack2(x0.x, x0.y); rk.y = pack2(x0.z, x0.w);
    rk.z = pack2(x1.x, x1.y); rk.w = pack2(x1.z, x1.w);
    *(uint4*)(vis_b + b*512 + lane*8) = rk;
    float ss = x0.x*x0.x + x0.y*x0.y + x0.z*x0.z + x0.w*x0.w
             + x1.x*x1.x + x1.y*x1.y + x1.z*x1.z + x1.w*x1.w;
    ss = wave_sum(ss);
    float inv = 1.0f / fmaxf(sqrtf(ss), EPS);
    float4 y0, y1;
    y0.x = x0.x*inv; y0.y = x0.y*inv; y0.z = x0.z*inv; y0.w = x0.w*inv;
    y1.x = x1.x*inv; y1.y = x1.y*inv; y1.z = x1.z*inv; y1.w = x1.w*inv;
    *(float4*)(vis_n + b*512 + lane*8)     = y0;
    *(float4*)(vis_n + b*512 + lane*8 + 4) = y1;
    uint4 pk;
    pk.x = pack2(y0.x, y0.y); pk.y = pack2(y0.z, y0.w);
    pk.z = pack2(y1.x, y1.y); pk.w = pack2(y1.z, y1.w);
    *(uint4*)(vis_nb + b*512 + lane*8) = pk;
}

// ---------- K2/K6/K8: C(MxN) = A(Mx512,bf16) @ B(Nx512,bf16)^T [+bias], fp32 out ----------
__global__ __launch_bounds__(256) void gemm64(const u16* __restrict__ A, int lda,
                                              const u16* __restrict__ B,
                                              const float* __restrict__ bias,
                                              float* __restrict__ Cf, int ldc)
{
    __shared__ __align__(16) u16 As[64 * 64];
    __shared__ __align__(16) u16 Bs[64 * 64];
    const int t = threadIdx.x, lane = t & 63, w = t >> 6;
    const int m0 = blockIdx.x * 64, n0 = blockIdx.y * 64;
    const int wm = (w >> 1) * 32, wn = (w & 1) * 32;
    const int l16 = lane & 15, quad = lane >> 4;
    const int srow = t >> 3, scol = (t & 7) * 8;

    f32x4 acc[2][2];
    for (int i = 0; i < 2; i++)
        for (int j = 0; j < 2; j++)
            for (int e = 0; e < 4; e++) acc[i][j][e] = 0.f;

    for (int ko = 0; ko < 512; ko += 64) {
        __syncthreads();
        #pragma unroll
        for (int i = 0; i < 2; i++) {
            int row = i * 32 + srow;
            *(uint4*)&As[row * 64 + scol] = *(const uint4*)&A[(size_t)(m0 + row) * lda + ko + scol];
            *(uint4*)&Bs[row * 64 + scol] = *(const uint4*)&B[(size_t)(n0 + row) * 512 + ko + scol];
        }
        __syncthreads();
        #pragma unroll
        for (int ks = 0; ks < 2; ks++) {
            short8 af[2], bfr[2];
            #pragma unroll
            for (int i = 0; i < 2; i++)
                af[i] = *(const short8*)&As[(wm + i * 16 + l16) * 64 + ks * 32 + quad * 8];
            #pragma unroll
            for (int j = 0; j < 2; j++)
                bfr[j] = *(const short8*)&Bs[(wn + j * 16 + l16) * 64 + ks * 32 + quad * 8];
            #pragma unroll
            for (int i = 0; i < 2; i++)
                #pragma unroll
                for (int j = 0; j < 2; j++)
                    acc[i][j] = __builtin_amdgcn_mfma_f32_16x16x32_bf16(af[i], bfr[j], acc[i][j], 0, 0, 0);
        }
    }
    for (int i = 0; i < 2; i++) {
        int row = m0 + wm + i * 16 + quad * 4;
        for (int j = 0; j < 2; j++) {
            int col = n0 + wn + j * 16 + l16;
            float bv = bias ? bias[col] : 0.f;
            for (int r = 0; r < 4; r++)
                Cf[(size_t)(row + r) * ldc + col] = acc[i][j][r] + bv;
        }
    }
}

// ---------- K5: ctx_h(512x64) = u_h(512x512) @ Wv_h(64x512)^T + bv_h, bf16 out ----------
__global__ __launch_bounds__(256) void gemm_head(const u16* __restrict__ u_allb,
                                                 const u16* __restrict__ wvb,
                                                 const float* __restrict__ bv,
                                                 u16* __restrict__ ctxb)
{
    const int h = blockIdx.y;
    const u16* A = u_allb + h * 512;                 // lda 4096
    const u16* B = wvb + (size_t)h * 64 * 512;       // 64 rows, ldb 512
    __shared__ __align__(16) u16 As[64 * 64];
    __shared__ __align__(16) u16 Bs[64 * 64];
    const int t = threadIdx.x, lane = t & 63, w = t >> 6;
    const int m0 = blockIdx.x * 64;
    const int wm = (w >> 1) * 32, wn = (w & 1) * 32;
    const int l16 = lane & 15, quad = lane >> 4;
    const int srow = t >> 3, scol = (t & 7) * 8;

    f32x4 acc[2][2];
    for (int i = 0; i < 2; i++)
        for (int j = 0; j < 2; j++)
            for (int e = 0; e < 4; e++) acc[i][j][e] = 0.f;

    for (int ko = 0; ko < 512; ko += 64) {
        __syncthreads();
        #pragma unroll
        for (int i = 0; i < 2; i++) {
            int row = i * 32 + srow;
            *(uint4*)&As[row * 64 + scol] = *(const uint4*)&A[(size_t)(m0 + row) * 4096 + ko + scol];
            *(uint4*)&Bs[row * 64 + scol] = *(const uint4*)&B[(size_t)row * 512 + ko + scol];
        }
        __syncthreads();
        #pragma unroll
        for (int ks = 0; ks < 2; ks++) {
            short8 af[2], bfr[2];
            #pragma unroll
            for (int i = 0; i < 2; i++)
                af[i] = *(const short8*)&As[(wm + i * 16 + l16) * 64 + ks * 32 + quad * 8];
            #pragma unroll
            for (int j = 0; j < 2; j++)
                bfr[j] = *(const short8*)&Bs[(wn + j * 16 + l16) * 64 + ks * 32 + quad * 8];
            #pragma unroll
            for (int i = 0; i < 2; i++)
                #pragma unroll
                for (int j = 0; j < 2; j++)
                    acc[i][j] = __builtin_amdgcn_mfma_f32_16x16x32_bf16(af[i], bfr[j], acc[i][j], 0, 0, 0);
        }
    }
    for (int i = 0; i < 2; i++) {
        int row = m0 + wm + i * 16 + quad * 4;
        for (int j = 0; j < 2; j++) {
            int col = wn + j * 16 + l16;
            float bb = bv[h * 64 + col];
            for (int r = 0; r < 4; r++)
                ctxb[(size_t)(row + r) * 512 + h * 64 + col] = f2bf(acc[i][j][r] + bb);
        }
    }
}

// ---------- K3: qk_all[b,h,j] = sum_d q[b,h*64+d] * wk[h*64+d, j]  (fp32) ----------
__global__ __launch_bounds__(256) void qk_proj(const float* __restrict__ q,
                                               const float* __restrict__ wk,
                                               float* __restrict__ qk_all)
{
    int bg = blockIdx.x, h = blockIdx.y;
    int t = threadIdx.x;
    int j = blockIdx.z * 256 + t;
    __shared__ float q8[8][64];
    {
        int r = t >> 5;
        int d0 = (t & 31) * 2;
        const float* qp = q + (bg * 8 + r) * 512 + h * 64 + d0;
        q8[r][d0] = qp[0]; q8[r][d0 + 1] = qp[1];
    }
    __syncthreads();
    float acc[8] = {0, 0, 0, 0, 0, 0, 0, 0};
    const float* wrow = wk + (size_t)(h * 64) * 512 + j;
    #pragma unroll 4
    for (int d = 0; d < 64; d++) {
        float ww = wrow[(size_t)d * 512];
        #pragma unroll
        for (int r = 0; r < 8; r++) acc[r] += q8[r][d] * ww;
    }
    #pragma unroll
    for (int r = 0; r < 8; r++)
        qk_all[((size_t)(bg * 8 + r) * 8 + h) * 512 + j] = acc[r];
}

// ---------- K4: fused sims+cluster+attention via LDS-resident MFMA, 1 block/b ----------
__global__ __launch_bounds__(512) void fused_attn(const float* __restrict__ tf,
                                                  const float* __restrict__ vis_n,
                                                  const float* __restrict__ qk_all,
                                                  u16* __restrict__ u_allb,
                                                  float* __restrict__ out_cs)
{
    __shared__ __align__(16) u16 Xs[96 * 520];
    __shared__ __align__(16) u16 Qs[16 * 520];
    __shared__ __align__(16) u16 Ps[16 * 104];
    __shared__ float Sc[16 * 100];
    __shared__ float sm_[96], srt[96], linv[8];

    const int b = blockIdx.x;
    const int t = threadIdx.x, w = t >> 6, lane = t & 63;
    const int l16 = lane & 15, quad = lane >> 4;

    const float4* v4 = (const float4*)(vis_n + b * 512 + lane * 8);
    float4 va = v4[0], vb = v4[1];

    {
        const float4* q4 = (const float4*)(qk_all + ((size_t)b * 8 + w) * 512 + lane * 8);
        float4 a = q4[0], c = q4[1];
        uint4 pk;
        pk.x = pack2(a.x, a.y); pk.y = pack2(a.z, a.w);
        pk.z = pack2(c.x, c.y); pk.w = pack2(c.z, c.w);
        *(uint4*)&Qs[w * 520 + lane * 8] = pk;
    }

    // stage Xs + sims, 2 rows per iteration for 4-chain ILP
    #pragma unroll 2
    for (int i = 0; i < 6; i++) {
        int m0r = w + i * 16;
        int m1r = m0r + 8;
        const float4* x4a = (const float4*)(tf + ((size_t)b * 96 + m0r) * 512 + lane * 8);
        const float4* x4b = (const float4*)(tf + ((size_t)b * 96 + m1r) * 512 + lane * 8);
        float4 a0 = x4a[0], c0 = x4a[1];
        float4 a1 = x4b[0], c1 = x4b[1];
        float ss0 = a0.x*a0.x + a0.y*a0.y + a0.z*a0.z + a0.w*a0.w
                  + c0.x*c0.x + c0.y*c0.y + c0.z*c0.z + c0.w*c0.w;
        float dt0 = a0.x*va.x + a0.y*va.y + a0.z*va.z + a0.w*va.w
                  + c0.x*vb.x + c0.y*vb.y + c0.z*vb.z + c0.w*vb.w;
        float ss1 = a1.x*a1.x + a1.y*a1.y + a1.z*a1.z + a1.w*a1.w
                  + c1.x*c1.x + c1.y*c1.y + c1.z*c1.z + c1.w*c1.w;
        float dt1 = a1.x*va.x + a1.y*va.y + a1.z*va.z + a1.w*va.w
                  + c1.x*vb.x + c1.y*vb.y + c1.z*vb.z + c1.w*vb.w;
        #pragma unroll
        for (int off = 32; off; off >>= 1) {
            ss0 += __shfl_xor(ss0, off, 64);
            dt0 += __shfl_xor(dt0, off, 64);
            ss1 += __shfl_xor(ss1, off, 64);
            dt1 += __shfl_xor(dt1, off, 64);
        }
        if (lane == 0) {
            sm_[m0r] = dt0 / fmaxf(sqrtf(ss0), EPS);
            sm_[m1r] = dt1 / fmaxf(sqrtf(ss1), EPS);
        }
        uint4 pk0, pk1;
        pk0.x = pack2(a0.x, a0.y); pk0.y = pack2(a0.z, a0.w);
        pk0.z = pack2(c0.x, c0.y); pk0.w = pack2(c0.z, c0.w);
        pk1.x = pack2(a1.x, a1.y); pk1.y = pack2(a1.z, a1.w);
        pk1.z = pack2(c1.x, c1.y); pk1.w = pack2(c1.z, c1.w);
        *(uint4*)&Xs[m0r * 520 + lane * 8] = pk0;
        *(uint4*)&Xs[m1r * 520 + lane * 8] = pk1;
    }
    __syncthreads();

    if (w < 6) {
        f32x4 acc;
        for (int e = 0; e < 4; e++) acc[e] = 0.f;
        #pragma unroll
        for (int ks = 0; ks < 16; ks++) {
            short8 a = *(const short8*)&Xs[(w * 16 + l16) * 520 + ks * 32 + quad * 8];
            short8 q = *(const short8*)&Qs[l16 * 520 + ks * 32 + quad * 8];
            acc = __builtin_amdgcn_mfma_f32_16x16x32_bf16(a, q, acc, 0, 0, 0);
        }
        #pragma unroll
        for (int r = 0; r < 4; r++)
            Sc[l16 * 100 + w * 16 + quad * 4 + r] = acc[r] * 0.125f;
    }
    __syncthreads();

    {
        float e0 = __expf(Sc[w * 100 + lane]);
        float e1 = (lane < 32) ? __expf(Sc[w * 100 + 64 + lane]) : 0.f;
        float l = wave_sum(e0 + e1);
        Ps[w * 104 + lane] = f2bf(e0);
        if (lane < 32) Ps[w * 104 + 64 + lane] = f2bf(e1);
        if (lane == 0) linv[w] = 1.0f / l;
    }
    if (t < 96) {
        float v = sm_[t]; int r = 0;
        for (int j = 0; j < 96; j++) {
            float u = sm_[j];
            r += (u > v) || (u == v && j < t);
        }
        srt[r] = v;
    }
    __syncthreads();

    #pragma unroll
    for (int jj = 0; jj < 4; jj++) {
        int n0 = (w * 4 + jj) * 16;
        f32x4 acc;
        for (int e = 0; e < 4; e++) acc[e] = 0.f;
        #pragma unroll
        for (int ks = 0; ks < 3; ks++) {
            short8 ap = *(const short8*)&Ps[l16 * 104 + ks * 32 + quad * 8];
            short8 bx;
            #pragma unroll
            for (int j = 0; j < 8; j++)
                bx[j] = (short)Xs[(ks * 32 + quad * 8 + j) * 520 + n0 + l16];
            acc = __builtin_amdgcn_mfma_f32_16x16x32_bf16(ap, bx, acc, 0, 0, 0);
        }
        if (quad < 2) {
            #pragma unroll
            for (int r = 0; r < 4; r++) {
                int h = quad * 4 + r;
                u_allb[((size_t)b * 8 + h) * 512 + n0 + l16] = f2bf(acc[r] * linv[h]);
            }
        }
    }
    if (t < 3) {
        float mean = 0.f;
        #pragma unroll 8
        for (int i = 0; i < 32; i++) mean += srt[t * 32 + i];
        mean *= (1.0f / 32.0f);
        float var = 0.f;
        #pragma unroll 8
        for (int i = 0; i < 32; i++) { float d = srt[t * 32 + i] - mean; var += d * d; }
        var *= (1.0f / 31.0f);
        out_cs[b * 3 + t] = mean / (sqrtf(var) + 1e-6f);
    }
}

// ---------- K7: build normalized negatives (bf16) + pos_sim ----------
__global__ __launch_bounds__(256) void negs_build(const float* __restrict__ corrected,
                                                  const float* __restrict__ tm,
                                                  const float* __restrict__ vis_n,
                                                  u16* __restrict__ negs_nb,
                                                  float* __restrict__ pos)
{
    int wave = threadIdx.x >> 6, lane = threadIdx.x & 63;
    int j = blockIdx.x * 4 + wave;
    const float* src = (j < 512) ? (corrected + j * 512) : (tm + j * 512);
    const float* row = src + lane * 8;
    float4 x0 = *(const float4*)row;
    float4 x1 = *(const float4*)(row + 4);
    float ss = x0.x*x0.x + x0.y*x0.y + x0.z*x0.z + x0.w*x0.w
             + x1.x*x1.x + x1.y*x1.y + x1.z*x1.z + x1.w*x1.w;
    float dt = 0.f;
    if (j < 512) {
        const float* vn = vis_n + j * 512 + lane * 8;
        float4 v0 = *(const float4*)vn;
        float4 v1 = *(const float4*)(vn + 4);
        dt = x0.x*v0.x + x0.y*v0.y + x0.z*v0.z + x0.w*v0.w
           + x1.x*v1.x + x1.y*v1.y + x1.z*v1.z + x1.w*v1.w;
    }
    ss = wave_sum(ss);
    dt = wave_sum(dt);
    float inv = 1.0f / fmaxf(sqrtf(ss), EPS);
    float4 y0, y1;
    y0.x = x0.x*inv; y0.y = x0.y*inv; y0.z = x0.z*inv; y0.w = x0.w*inv;
    y1.x = x1.x*inv; y1.y = x1.y*inv; y1.z = x1.z*inv; y1.w = x1.w*inv;
    uint4 pk;
    pk.x = pack2(y0.x, y0.y); pk.y = pack2(y0.z, y0.w);
    pk.z = pack2(y1.x, y1.y); pk.w = pack2(y1.z, y1.w);
    *(uint4*)(negs_nb + j * 512 + lane * 8) = pk;
    if (j < 512 && lane == 0) pos[j] = dt * inv;
}

// ---------- K9: top-5 (1024 distinct, first 512 have multiplicity 2) + loss ----------
__global__ __launch_bounds__(256) void topk_loss(const float* __restrict__ ns,
                                                 const float* __restrict__ pos,
                                                 const float* __restrict__ tau_p_log,
                                                 const float* __restrict__ tau_n_log,
                                                 float* __restrict__ out_loss)
{
    int b = blockIdx.x, t = threadIdx.x;
    int w = t >> 6, lane = t & 63;
    __shared__ float cand_v[4];
    __shared__ int   cand_m[4];   // packed: (wave<<8)|lane ... and mult in high bits

    // load 4 distinct values per thread, sort desc in registers
    const float4 raw = *(const float4*)(ns + b * 1024 + t * 4);
    float lv[4] = {raw.x, raw.y, raw.z, raw.w};
    // insertion sort desc (4 elems)
    #pragma unroll
    for (int i = 1; i < 4; i++) {
        float key = lv[i];
        int j = i - 1;
        #pragma unroll
        for (int k = 0; k < 3; k++) {
            if (j >= 0 && lv[j] < key) { lv[j + 1] = lv[j]; j--; }
        }
        lv[j + 1] = key;
    }
    const int mult = (t < 128) ? 2 : 1;     // t*4 < 512 → corr sims appear twice
    int lp = 0;                              // pop pointer

    float tn = expf(tau_n_log[0]);
    float inv_tn = 1.0f / tn;
    float nsum = 0.f;
    int collected = 0;

    for (int round = 0; round < 5 && collected < 5; round++) {
        float head = (lp < 4) ? lv[lp] : -1e30f;
        // wave argmax: carry lane id alongside
        float mv = head; int ml = lane;
        #pragma unroll
        for (int off = 32; off; off >>= 1) {
            float ov = __shfl_xor(mv, off, 64);
            int   ol = __shfl_xor(ml, off, 64);
            if (ov > mv || (ov == mv && ol < ml)) { mv = ov; ml = ol; }
        }
        if (lane == 0) { cand_v[w] = mv; cand_m[w] = ml; }
        __syncthreads();
        // global winner (all threads compute identically)
        float bv = cand_v[0]; int bw = 0;
        #pragma unroll
        for (int i = 1; i < 4; i++) {
            if (cand_v[i] > bv) { bv = cand_v[i]; bw = i; }
        }
        int bl = cand_m[bw];
        __syncthreads();
        // owner pops
        if (w == bw && lane == bl) lp++;
        // winner's multiplicity: owner thread index = bw*64+bl
        int wm = ((bw * 64 + bl) < 128) ? 2 : 1;
        int take = (wm < (5 - collected)) ? wm : (5 - collected);
        nsum += (float)take * __expf(bv * inv_tn);
        collected += take;
    }

    if (t == 0) {
        float tp = expf(tau_p_log[0]);
        float p = expf(pos[b] / tp);
        float term = logf(p / (p + nsum + 1e-8f));
        atomicAdd(out_loss, -term * (1.0f / 512.0f));
    }
}

// ---------- launch ----------
extern "C" void kernel_launch(void* const* d_in, const int* in_sizes, int n_in,
                              void* d_out, int out_size, void* d_ws, size_t ws_size,
                              hipStream_t stream) {
    const float* vis = (const float*)d_in[0];
    const float* tf  = (const float*)d_in[1];
    const float* ipw = (const float*)d_in[2];
    const float* ipb = (const float*)d_in[3];
    const float* opw = (const float*)d_in[4];
    const float* opb = (const float*)d_in[5];
    const float* tm  = (const float*)d_in[6];
    const float* tpl = (const float*)d_in[7];
    const float* tnl = (const float*)d_in[8];

    float* out       = (float*)d_out;
    float* out_loss  = out;
    float* out_corr  = out + 1;                  // (512,512)
    float* out_cs    = out + 1 + 512 * 512;      // (512,3)

    char* p = (char*)d_ws;
    auto alloc = [&](size_t bytes) { char* r = p; p += (bytes + 255) & ~(size_t)255; return r; };
    float* vis_n  = (float*)alloc(512 * 512 * 4);
    u16*   vis_nb = (u16*)  alloc(512 * 512 * 2);
    u16*   vis_b  = (u16*)  alloc(512 * 512 * 2);
    u16*   wqb    = (u16*)  alloc(512 * 512 * 2);
    u16*   wvb    = (u16*)  alloc(512 * 512 * 2);
    u16*   wob    = (u16*)  alloc(512 * 512 * 2);
    float* qws    = (float*)alloc(512 * 512 * 4);
    float* qk_all = (float*)alloc((size_t)512 * 8 * 512 * 4);
    u16*   u_allb = (u16*)  alloc((size_t)512 * 8 * 512 * 2);
    u16*   ctxb   = (u16*)  alloc(512 * 512 * 2);
    u16*   negsb  = (u16*)  alloc(1024 * 512 * 2);
    float* ns     = (float*)alloc(512 * 1024 * 4);
    float* pos    = (float*)alloc(512 * 4);

    const float* wk = ipw + 512 * 512;           // fp32 rows 512..1023
    const float* bv = ipb + 2 * 512;

    prep<<<896, 256, 0, stream>>>(vis, ipw, opw, vis_n, vis_nb, vis_b, wqb, wvb, wob, out_loss);
    gemm64<<<dim3(8, 8), 256, 0, stream>>>(vis_b, 512, wqb, ipb, qws, 512);        // q
    qk_proj<<<dim3(64, 8, 2), 256, 0, stream>>>(qws, wk, qk_all);
    fused_attn<<<512, 512, 0, stream>>>(tf, vis_n, qk_all, u_allb, out_cs);
    gemm_head<<<dim3(8, 8), 256, 0, stream>>>(u_allb, wvb, bv, ctxb);              // ctx (bf16)
    gemm64<<<dim3(8, 8), 256, 0, stream>>>(ctxb, 512, wob, opb, out_corr, 512);    // corrected
    negs_build<<<256, 256, 0, stream>>>(out_corr, tm, vis_n, negsb, pos);
    gemm64<<<dim3(8, 16), 256, 0, stream>>>(vis_nb, 512, negsb, nullptr, ns, 1024);
    topk_loss<<<512, 256, 0, stream>>>(ns, pos, tpl, tnl, out_loss);
}

// Round 5
// 244.207 us; speedup vs baseline: 1.5062x; 1.0259x over previous
//
#include <hip/hip_runtime.h>
#include <math.h>

typedef unsigned short u16;
typedef unsigned int u32;
typedef __attribute__((ext_vector_type(8))) short short8;   // 8 bf16 (4 VGPRs) MFMA A/B frag
typedef __attribute__((ext_vector_type(4))) float f32x4;    // MFMA C/D frag

#define EPS 1e-8f

// ---------- helpers ----------
__device__ inline float bf2f(u16 u) {
    union { u32 i; float f; } v; v.i = ((u32)u) << 16; return v.f;
}
__device__ inline u16 f2bf(float f) {  // RNE
    union { float f; u32 u; } v; v.f = f;
    u32 r = v.u + 0x7fffu + ((v.u >> 16) & 1u);
    return (u16)(r >> 16);
}
__device__ inline u32 pack2(float a, float b) {
    return (u32)f2bf(a) | ((u32)f2bf(b) << 16);
}
__device__ inline float wave_sum(float v) {
    for (int off = 32; off; off >>= 1) v += __shfl_xor(v, off, 64);
    return v;
}

// ---------- K1: prep = vis normalize (fp32+bf16) + raw bf16 + Wq/Wv/Wo cvt ----------
__global__ __launch_bounds__(256) void prep(const float* __restrict__ vis,
                                            const float* __restrict__ ipw,
                                            const float* __restrict__ opw,
                                            float* __restrict__ vis_n,
                                            u16* __restrict__ vis_nb,
                                            u16* __restrict__ vis_b,
                                            u16* __restrict__ wqb,
                                            u16* __restrict__ wvb,
                                            u16* __restrict__ wob,
                                            float* __restrict__ loss0)
{
    int bid = blockIdx.x;
    if (bid >= 128) {
        int i = ((bid - 128) * 256 + threadIdx.x) * 4;   // 786432 elems
        const float* src; u16* dst; int j;
        if (i < 262144)      { j = i;          src = ipw + j;          dst = wqb + j; }
        else if (i < 524288) { j = i - 262144; src = ipw + 524288 + j; dst = wvb + j; }
        else                 { j = i - 524288; src = opw + j;          dst = wob + j; }
        float4 v = *(const float4*)src;
        uint2 pk; pk.x = pack2(v.x, v.y); pk.y = pack2(v.z, v.w);
        *(uint2*)dst = pk;
        return;
    }
    if (bid == 0 && threadIdx.x == 0) loss0[0] = 0.0f;
    int wave = threadIdx.x >> 6, lane = threadIdx.x & 63;
    int b = bid * 4 + wave;                      // B = 512
    const float* row = vis + b * 512 + lane * 8;
    float4 x0 = *(const float4*)row;
    float4 x1 = *(const float4*)(row + 4);
    uint4 rk;
    rk.x = pack2(x0.x, x0.y); rk.y = pack2(x0.z, x0.w);
    rk.z = pack2(x1.x, x1.y); rk.w = pack2(x1.z, x1.w);
    *(uint4*)(vis_b + b*512 + lane*8) = rk;
    float ss = x0.x*x0.x + x0.y*x0.y + x0.z*x0.z + x0.w*x0.w
             + x1.x*x1.x + x1.y*x1.y + x1.z*x1.z + x1.w*x1.w;
    ss = wave_sum(ss);
    float inv = 1.0f / fmaxf(sqrtf(ss), EPS);
    float4 y0, y1;
    y0.x = x0.x*inv; y0.y = x0.y*inv; y0.z = x0.z*inv; y0.w = x0.w*inv;
    y1.x = x1.x*inv; y1.y = x1.y*inv; y1.z = x1.z*inv; y1.w = x1.w*inv;
    *(float4*)(vis_n + b*512 + lane*8)     = y0;
    *(float4*)(vis_n + b*512 + lane*8 + 4) = y1;
    uint4 pk;
    pk.x = pack2(y0.x, y0.y); pk.y = pack2(y0.z, y0.w);
    pk.z = pack2(y1.x, y1.y); pk.w = pack2(y1.z, y1.w);
    *(uint4*)(vis_nb + b*512 + lane*8) = pk;
}

// ---------- K2/K6/K8: C(MxN) = A(Mx512,bf16) @ B(Nx512,bf16)^T [+bias], fp32 out ----------
__global__ __launch_bounds__(256) void gemm64(const u16* __restrict__ A, int lda,
                                              const u16* __restrict__ B,
                                              const float* __restrict__ bias,
                                              float* __restrict__ Cf, int ldc)
{
    __shared__ __align__(16) u16 As[64 * 64];
    __shared__ __align__(16) u16 Bs[64 * 64];
    const int t = threadIdx.x, lane = t & 63, w = t >> 6;
    const int m0 = blockIdx.x * 64, n0 = blockIdx.y * 64;
    const int wm = (w >> 1) * 32, wn = (w & 1) * 32;
    const int l16 = lane & 15, quad = lane >> 4;
    const int srow = t >> 3, scol = (t & 7) * 8;

    f32x4 acc[2][2];
    for (int i = 0; i < 2; i++)
        for (int j = 0; j < 2; j++)
            for (int e = 0; e < 4; e++) acc[i][j][e] = 0.f;

    for (int ko = 0; ko < 512; ko += 64) {
        __syncthreads();
        #pragma unroll
        for (int i = 0; i < 2; i++) {
            int row = i * 32 + srow;
            *(uint4*)&As[row * 64 + scol] = *(const uint4*)&A[(size_t)(m0 + row) * lda + ko + scol];
            *(uint4*)&Bs[row * 64 + scol] = *(const uint4*)&B[(size_t)(n0 + row) * 512 + ko + scol];
        }
        __syncthreads();
        #pragma unroll
        for (int ks = 0; ks < 2; ks++) {
            short8 af[2], bfr[2];
            #pragma unroll
            for (int i = 0; i < 2; i++)
                af[i] = *(const short8*)&As[(wm + i * 16 + l16) * 64 + ks * 32 + quad * 8];
            #pragma unroll
            for (int j = 0; j < 2; j++)
                bfr[j] = *(const short8*)&Bs[(wn + j * 16 + l16) * 64 + ks * 32 + quad * 8];
            #pragma unroll
            for (int i = 0; i < 2; i++)
                #pragma unroll
                for (int j = 0; j < 2; j++)
                    acc[i][j] = __builtin_amdgcn_mfma_f32_16x16x32_bf16(af[i], bfr[j], acc[i][j], 0, 0, 0);
        }
    }
    for (int i = 0; i < 2; i++) {
        int row = m0 + wm + i * 16 + quad * 4;
        for (int j = 0; j < 2; j++) {
            int col = n0 + wn + j * 16 + l16;
            float bv = bias ? bias[col] : 0.f;
            for (int r = 0; r < 4; r++)
                Cf[(size_t)(row + r) * ldc + col] = acc[i][j][r] + bv;
        }
    }
}

// ---------- K5: ctx_h(512x64) = u_h(512x512) @ Wv_h(64x512)^T + bv_h, bf16 out ----------
__global__ __launch_bounds__(256) void gemm_head(const u16* __restrict__ u_allb,
                                                 const u16* __restrict__ wvb,
                                                 const float* __restrict__ bv,
                                                 u16* __restrict__ ctxb)
{
    const int h = blockIdx.y;
    const u16* A = u_allb + h * 512;                 // lda 4096
    const u16* B = wvb + (size_t)h * 64 * 512;       // 64 rows, ldb 512
    __shared__ __align__(16) u16 As[64 * 64];
    __shared__ __align__(16) u16 Bs[64 * 64];
    const int t = threadIdx.x, lane = t & 63, w = t >> 6;
    const int m0 = blockIdx.x * 64;
    const int wm = (w >> 1) * 32, wn = (w & 1) * 32;
    const int l16 = lane & 15, quad = lane >> 4;
    const int srow = t >> 3, scol = (t & 7) * 8;

    f32x4 acc[2][2];
    for (int i = 0; i < 2; i++)
        for (int j = 0; j < 2; j++)
            for (int e = 0; e < 4; e++) acc[i][j][e] = 0.f;

    for (int ko = 0; ko < 512; ko += 64) {
        __syncthreads();
        #pragma unroll
        for (int i = 0; i < 2; i++) {
            int row = i * 32 + srow;
            *(uint4*)&As[row * 64 + scol] = *(const uint4*)&A[(size_t)(m0 + row) * 4096 + ko + scol];
            *(uint4*)&Bs[row * 64 + scol] = *(const uint4*)&B[(size_t)row * 512 + ko + scol];
        }
        __syncthreads();
        #pragma unroll
        for (int ks = 0; ks < 2; ks++) {
            short8 af[2], bfr[2];
            #pragma unroll
            for (int i = 0; i < 2; i++)
                af[i] = *(const short8*)&As[(wm + i * 16 + l16) * 64 + ks * 32 + quad * 8];
            #pragma unroll
            for (int j = 0; j < 2; j++)
                bfr[j] = *(const short8*)&Bs[(wn + j * 16 + l16) * 64 + ks * 32 + quad * 8];
            #pragma unroll
            for (int i = 0; i < 2; i++)
                #pragma unroll
                for (int j = 0; j < 2; j++)
                    acc[i][j] = __builtin_amdgcn_mfma_f32_16x16x32_bf16(af[i], bfr[j], acc[i][j], 0, 0, 0);
        }
    }
    for (int i = 0; i < 2; i++) {
        int row = m0 + wm + i * 16 + quad * 4;
        for (int j = 0; j < 2; j++) {
            int col = wn + j * 16 + l16;
            float bb = bv[h * 64 + col];
            for (int r = 0; r < 4; r++)
                ctxb[(size_t)(row + r) * 512 + h * 64 + col] = f2bf(acc[i][j][r] + bb);
        }
    }
}

// ---------- K3: qk_all[b,h,j] = sum_d q[b,h*64+d] * wk[h*64+d, j]  (fp32) ----------
__global__ __launch_bounds__(256) void qk_proj(const float* __restrict__ q,
                                               const float* __restrict__ wk,
                                               float* __restrict__ qk_all)
{
    int bg = blockIdx.x, h = blockIdx.y;
    int t = threadIdx.x;
    int j = blockIdx.z * 256 + t;
    __shared__ float q8[8][64];
    {
        int r = t >> 5;
        int d0 = (t & 31) * 2;
        const float* qp = q + (bg * 8 + r) * 512 + h * 64 + d0;
        q8[r][d0] = qp[0]; q8[r][d0 + 1] = qp[1];
    }
    __syncthreads();
    float acc[8] = {0, 0, 0, 0, 0, 0, 0, 0};
    const float* wrow = wk + (size_t)(h * 64) * 512 + j;
    #pragma unroll 4
    for (int d = 0; d < 64; d++) {
        float ww = wrow[(size_t)d * 512];
        #pragma unroll
        for (int r = 0; r < 8; r++) acc[r] += q8[r][d] * ww;
    }
    #pragma unroll
    for (int r = 0; r < 8; r++)
        qk_all[((size_t)(bg * 8 + r) * 8 + h) * 512 + j] = acc[r];
}

// ---------- K4: fused sims+cluster+attention, 1024 threads (16 waves), 1 block/b ----------
__global__ __launch_bounds__(1024) void fused_attn(const float* __restrict__ tf,
                                                   const float* __restrict__ vis_n,
                                                   const float* __restrict__ qk_all,
                                                   u16* __restrict__ u_allb,
                                                   float* __restrict__ out_cs)
{
    __shared__ __align__(16) u16 Xs[96 * 520];
    __shared__ __align__(16) u16 Qs[16 * 520];
    __shared__ __align__(16) u16 Ps[16 * 104];
    __shared__ float Sc[16 * 100];
    __shared__ float sm_[96], srt[96], linv[8];

    const int b = blockIdx.x;
    const int t = threadIdx.x, w = t >> 6, lane = t & 63;
    const int l16 = lane & 15, quad = lane >> 4;

    const float4* v4 = (const float4*)(vis_n + b * 512 + lane * 8);
    float4 va = v4[0], vb = v4[1];

    if (w < 8) {
        const float4* q4 = (const float4*)(qk_all + ((size_t)b * 8 + w) * 512 + lane * 8);
        float4 a = q4[0], c = q4[1];
        uint4 pk;
        pk.x = pack2(a.x, a.y); pk.y = pack2(a.z, a.w);
        pk.z = pack2(c.x, c.y); pk.w = pack2(c.z, c.w);
        *(uint4*)&Qs[w * 520 + lane * 8] = pk;
    }

    // stage Xs + sims; 16 waves x 6 rows each, 2 rows/iter for 4-chain ILP
    #pragma unroll
    for (int i = 0; i < 3; i++) {
        int m0r = w + i * 32;
        int m1r = m0r + 16;
        const float4* x4a = (const float4*)(tf + ((size_t)b * 96 + m0r) * 512 + lane * 8);
        const float4* x4b = (const float4*)(tf + ((size_t)b * 96 + m1r) * 512 + lane * 8);
        float4 a0 = x4a[0], c0 = x4a[1];
        float4 a1 = x4b[0], c1 = x4b[1];
        float ss0 = a0.x*a0.x + a0.y*a0.y + a0.z*a0.z + a0.w*a0.w
                  + c0.x*c0.x + c0.y*c0.y + c0.z*c0.z + c0.w*c0.w;
        float dt0 = a0.x*va.x + a0.y*va.y + a0.z*va.z + a0.w*va.w
                  + c0.x*vb.x + c0.y*vb.y + c0.z*vb.z + c0.w*vb.w;
        float ss1 = a1.x*a1.x + a1.y*a1.y + a1.z*a1.z + a1.w*a1.w
                  + c1.x*c1.x + c1.y*c1.y + c1.z*c1.z + c1.w*c1.w;
        float dt1 = a1.x*va.x + a1.y*va.y + a1.z*va.z + a1.w*va.w
                  + c1.x*vb.x + c1.y*vb.y + c1.z*vb.z + c1.w*vb.w;
        #pragma unroll
        for (int off = 32; off; off >>= 1) {
            ss0 += __shfl_xor(ss0, off, 64);
            dt0 += __shfl_xor(dt0, off, 64);
            ss1 += __shfl_xor(ss1, off, 64);
            dt1 += __shfl_xor(dt1, off, 64);
        }
        if (lane == 0) {
            sm_[m0r] = dt0 / fmaxf(sqrtf(ss0), EPS);
            sm_[m1r] = dt1 / fmaxf(sqrtf(ss1), EPS);
        }
        uint4 pk0, pk1;
        pk0.x = pack2(a0.x, a0.y); pk0.y = pack2(a0.z, a0.w);
        pk0.z = pack2(c0.x, c0.y); pk0.w = pack2(c0.z, c0.w);
        pk1.x = pack2(a1.x, a1.y); pk1.y = pack2(a1.z, a1.w);
        pk1.z = pack2(c1.x, c1.y); pk1.w = pack2(c1.z, c1.w);
        *(uint4*)&Xs[m0r * 520 + lane * 8] = pk0;
        *(uint4*)&Xs[m1r * 520 + lane * 8] = pk1;
    }
    __syncthreads();

    // scores: Sc[h=l16][m] = (X @ qk^T)/8 ; waves 0..5 take the 6 m-tiles
    if (w < 6) {
        f32x4 acc;
        for (int e = 0; e < 4; e++) acc[e] = 0.f;
        #pragma unroll
        for (int ks = 0; ks < 16; ks++) {
            short8 a = *(const short8*)&Xs[(w * 16 + l16) * 520 + ks * 32 + quad * 8];
            short8 q = *(const short8*)&Qs[l16 * 520 + ks * 32 + quad * 8];
            acc = __builtin_amdgcn_mfma_f32_16x16x32_bf16(a, q, acc, 0, 0, 0);
        }
        #pragma unroll
        for (int r = 0; r < 4; r++)
            Sc[l16 * 100 + w * 16 + quad * 4 + r] = acc[r] * 0.125f;
    }
    __syncthreads();

    // softmax (wave w = head w, w<8) -> Ps (unnormalized exp, bf16) + linv
    if (w < 8) {
        float e0 = __expf(Sc[w * 100 + lane]);
        float e1 = (lane < 32) ? __expf(Sc[w * 100 + 64 + lane]) : 0.f;
        float l = wave_sum(e0 + e1);
        Ps[w * 104 + lane] = f2bf(e0);
        if (lane < 32) Ps[w * 104 + 64 + lane] = f2bf(e1);
        if (lane == 0) linv[w] = 1.0f / l;
    }
    if (t < 96) {
        float v = sm_[t]; int r = 0;
        for (int j = 0; j < 96; j++) {
            float u = sm_[j];
            r += (u > v) || (u == v && j < t);
        }
        srt[r] = v;
    }
    __syncthreads();

    // u GEMM: u[h][d] = P(8x96) @ X(96x512); 16 waves x 2 n-tiles
    #pragma unroll
    for (int jj = 0; jj < 2; jj++) {
        int n0 = (w * 2 + jj) * 16;
        f32x4 acc;
        for (int e = 0; e < 4; e++) acc[e] = 0.f;
        #pragma unroll
        for (int ks = 0; ks < 3; ks++) {
            short8 ap = *(const short8*)&Ps[l16 * 104 + ks * 32 + quad * 8];
            short8 bx;
            #pragma unroll
            for (int j = 0; j < 8; j++)
                bx[j] = (short)Xs[(ks * 32 + quad * 8 + j) * 520 + n0 + l16];
            acc = __builtin_amdgcn_mfma_f32_16x16x32_bf16(ap, bx, acc, 0, 0, 0);
        }
        if (quad < 2) {
            #pragma unroll
            for (int r = 0; r < 4; r++) {
                int h = quad * 4 + r;
                u_allb[((size_t)b * 8 + h) * 512 + n0 + l16] = f2bf(acc[r] * linv[h]);
            }
        }
    }
    if (t < 3) {
        float mean = 0.f;
        #pragma unroll 8
        for (int i = 0; i < 32; i++) mean += srt[t * 32 + i];
        mean *= (1.0f / 32.0f);
        float var = 0.f;
        #pragma unroll 8
        for (int i = 0; i < 32; i++) { float d = srt[t * 32 + i] - mean; var += d * d; }
        var *= (1.0f / 31.0f);
        out_cs[b * 3 + t] = mean / (sqrtf(var) + 1e-6f);
    }
}

// ---------- K7: build normalized negatives (bf16) + pos_sim ----------
__global__ __launch_bounds__(256) void negs_build(const float* __restrict__ corrected,
                                                  const float* __restrict__ tm,
                                                  const float* __restrict__ vis_n,
                                                  u16* __restrict__ negs_nb,
                                                  float* __restrict__ pos)
{
    int wave = threadIdx.x >> 6, lane = threadIdx.x & 63;
    int j = blockIdx.x * 4 + wave;
    const float* src = (j < 512) ? (corrected + j * 512) : (tm + j * 512);
    const float* row = src + lane * 8;
    float4 x0 = *(const float4*)row;
    float4 x1 = *(const float4*)(row + 4);
    float ss = x0.x*x0.x + x0.y*x0.y + x0.z*x0.z + x0.w*x0.w
             + x1.x*x1.x + x1.y*x1.y + x1.z*x1.z + x1.w*x1.w;
    float dt = 0.f;
    if (j < 512) {
        const float* vn = vis_n + j * 512 + lane * 8;
        float4 v0 = *(const float4*)vn;
        float4 v1 = *(const float4*)(vn + 4);
        dt = x0.x*v0.x + x0.y*v0.y + x0.z*v0.z + x0.w*v0.w
           + x1.x*v1.x + x1.y*v1.y + x1.z*v1.z + x1.w*v1.w;
    }
    ss = wave_sum(ss);
    dt = wave_sum(dt);
    float inv = 1.0f / fmaxf(sqrtf(ss), EPS);
    float4 y0, y1;
    y0.x = x0.x*inv; y0.y = x0.y*inv; y0.z = x0.z*inv; y0.w = x0.w*inv;
    y1.x = x1.x*inv; y1.y = x1.y*inv; y1.z = x1.z*inv; y1.w = x1.w*inv;
    uint4 pk;
    pk.x = pack2(y0.x, y0.y); pk.y = pack2(y0.z, y0.w);
    pk.z = pack2(y1.x, y1.y); pk.w = pack2(y1.z, y1.w);
    *(uint4*)(negs_nb + j * 512 + lane * 8) = pk;
    if (j < 512 && lane == 0) pos[j] = dt * inv;
}

// ---------- K9: top-5 (1024 distinct, first 512 have multiplicity 2) + loss ----------
__global__ __launch_bounds__(256) void topk_loss(const float* __restrict__ ns,
                                                 const float* __restrict__ pos,
                                                 const float* __restrict__ tau_p_log,
                                                 const float* __restrict__ tau_n_log,
                                                 float* __restrict__ out_loss)
{
    int b = blockIdx.x, t = threadIdx.x;
    int w = t >> 6, lane = t & 63;
    __shared__ float cand_v[4];
    __shared__ int   cand_m[4];

    const float4 raw = *(const float4*)(ns + b * 1024 + t * 4);
    float lv[4] = {raw.x, raw.y, raw.z, raw.w};
    #pragma unroll
    for (int i = 1; i < 4; i++) {
        float key = lv[i];
        int j = i - 1;
        #pragma unroll
        for (int k = 0; k < 3; k++) {
            if (j >= 0 && lv[j] < key) { lv[j + 1] = lv[j]; j--; }
        }
        lv[j + 1] = key;
    }
    int lp = 0;

    float tn = expf(tau_n_log[0]);
    float inv_tn = 1.0f / tn;
    float nsum = 0.f;
    int collected = 0;

    for (int round = 0; round < 5 && collected < 5; round++) {
        float head = (lp < 4) ? lv[lp] : -1e30f;
        float mv = head; int ml = lane;
        #pragma unroll
        for (int off = 32; off; off >>= 1) {
            float ov = __shfl_xor(mv, off, 64);
            int   ol = __shfl_xor(ml, off, 64);
            if (ov > mv || (ov == mv && ol < ml)) { mv = ov; ml = ol; }
        }
        if (lane == 0) { cand_v[w] = mv; cand_m[w] = ml; }
        __syncthreads();
        float bv = cand_v[0]; int bw = 0;
        #pragma unroll
        for (int i = 1; i < 4; i++) {
            if (cand_v[i] > bv) { bv = cand_v[i]; bw = i; }
        }
        int bl = cand_m[bw];
        __syncthreads();
        if (w == bw && lane == bl) lp++;
        int wm = ((bw * 64 + bl) < 128) ? 2 : 1;
        int take = (wm < (5 - collected)) ? wm : (5 - collected);
        nsum += (float)take * __expf(bv * inv_tn);
        collected += take;
    }

    if (t == 0) {
        float tp = expf(tau_p_log[0]);
        float p = expf(pos[b] / tp);
        float term = logf(p / (p + nsum + 1e-8f));
        atomicAdd(out_loss, -term * (1.0f / 512.0f));
    }
}

// ---------- launch ----------
extern "C" void kernel_launch(void* const* d_in, const int* in_sizes, int n_in,
                              void* d_out, int out_size, void* d_ws, size_t ws_size,
                              hipStream_t stream) {
    const float* vis = (const float*)d_in[0];
    const float* tf  = (const float*)d_in[1];
    const float* ipw = (const float*)d_in[2];
    const float* ipb = (const float*)d_in[3];
    const float* opw = (const float*)d_in[4];
    const float* opb = (const float*)d_in[5];
    const float* tm  = (const float*)d_in[6];
    const float* tpl = (const float*)d_in[7];
    const float* tnl = (const float*)d_in[8];

    float* out       = (float*)d_out;
    float* out_loss  = out;
    float* out_corr  = out + 1;                  // (512,512)
    float* out_cs    = out + 1 + 512 * 512;      // (512,3)

    char* p = (char*)d_ws;
    auto alloc = [&](size_t bytes) { char* r = p; p += (bytes + 255) & ~(size_t)255; return r; };
    float* vis_n  = (float*)alloc(512 * 512 * 4);
    u16*   vis_nb = (u16*)  alloc(512 * 512 * 2);
    u16*   vis_b  = (u16*)  alloc(512 * 512 * 2);
    u16*   wqb    = (u16*)  alloc(512 * 512 * 2);
    u16*   wvb    = (u16*)  alloc(512 * 512 * 2);
    u16*   wob    = (u16*)  alloc(512 * 512 * 2);
    float* qws    = (float*)alloc(512 * 512 * 4);
    float* qk_all = (float*)alloc((size_t)512 * 8 * 512 * 4);
    u16*   u_allb = (u16*)  alloc((size_t)512 * 8 * 512 * 2);
    u16*   ctxb   = (u16*)  alloc(512 * 512 * 2);
    u16*   negsb  = (u16*)  alloc(1024 * 512 * 2);
    float* ns     = (float*)alloc(512 * 1024 * 4);
    float* pos    = (float*)alloc(512 * 4);

    const float* wk = ipw + 512 * 512;           // fp32 rows 512..1023
    const float* bv = ipb + 2 * 512;

    prep<<<896, 256, 0, stream>>>(vis, ipw, opw, vis_n, vis_nb, vis_b, wqb, wvb, wob, out_loss);
    gemm64<<<dim3(8, 8), 256, 0, stream>>>(vis_b, 512, wqb, ipb, qws, 512);        // q
    qk_proj<<<dim3(64, 8, 2), 256, 0, stream>>>(qws, wk, qk_all);
    fused_attn<<<512, 1024, 0, stream>>>(tf, vis_n, qk_all, u_allb, out_cs);
    gemm_head<<<dim3(8, 8), 256, 0, stream>>>(u_allb, wvb, bv, ctxb);              // ctx (bf16)
    gemm64<<<dim3(8, 8), 256, 0, stream>>>(ctxb, 512, wob, opb, out_corr, 512);    // corrected
    negs_build<<<256, 256, 0, stream>>>(out_corr, tm, vis_n, negsb, pos);
    gemm64<<<dim3(8, 16), 256, 0, stream>>>(vis_nb, 512, negsb, nullptr, ns, 1024);
    topk_loss<<<512, 256, 0, stream>>>(ns, pos, tpl, tnl, out_loss);
}